// Round 10
// baseline (365.054 us; speedup 1.0000x reference)
//
#include <hip/hip_runtime.h>
#include <cstddef>
#include <cstdint>

#define NG   100
#define NPG  1000
#define NN   (NG * NPG)       // 100000 nodes
#define NE   (NN * 16)        // 1600000 edges
#define EPG  (NE / NG)        // 16000 edges per graph (edges are graph-local)
#define FIN  64
#define HID  128
#define RD   64
#define SLOPE 0.01f
#define EPSV  1e-5f
#define NSTRIP 250            // nodes per GEMM/phi block (4 strips per graph)
#define GSN   40              // nodes per gather block (25 strips per graph)

using short8 = __attribute__((ext_vector_type(8))) short;   // 8 bf16 = 4 VGPRs
using f32x4  = __attribute__((ext_vector_type(4))) float;
typedef unsigned short u16;

__device__ __forceinline__ float leaky(float x) { return x >= 0.f ? x : SLOPE * x; }

// fp32 -> bf16 (round-to-nearest-even), bit pattern
__device__ __forceinline__ u16 f2bf(float f) {
  union { float f; unsigned u; } v; v.f = f;
  return (u16)((v.u + 0x7fffu + ((v.u >> 16) & 1u)) >> 16);
}
__device__ __forceinline__ float bf2f(u16 u) {
  union { unsigned u; float f; } v; v.u = ((unsigned)u) << 16;
  return v.f;
}

// XCD-affinity swizzle: block->XCD heuristic is blockIdx%8; pin graph g to
// XCD g%8 so producer/consumer blocks of one graph share an L2.
__device__ __forceinline__ bool swz(int b, int per_g, int& g, int& part) {
  const int xcd = b & 7;
  const int slot = b >> 3;
  g = xcd + 8 * (slot / per_g);
  part = slot % per_g;
  return g < NG;
}

// ---------------------------------------------------------------------------
// One-shot bf16 transpose of the four GEMM weight matrices: Wt[n][k]=W[k][n].
// ---------------------------------------------------------------------------
__global__ __launch_bounds__(256) void wt_k(const float* __restrict__ W1,
                                            const float* __restrict__ W2,
                                            const float* __restrict__ R1,
                                            const float* __restrict__ R2,
                                            u16* __restrict__ Wt1,
                                            u16* __restrict__ Wt2,
                                            u16* __restrict__ Rt1,
                                            u16* __restrict__ Rt2) {
  const int idx = blockIdx.x * 256 + threadIdx.x;  // 57344 total
  if (idx < FIN * HID) {
    const int n = idx >> 6, k = idx & 63;          // Wt1 [128][64]
    Wt1[idx] = f2bf(W1[k * HID + n]);
  } else {
    const int j = idx - FIN * HID;
    const int m = j >> 14, r = j & 16383;
    const int n = r >> 7, k = r & 127;
    const float* s = (m == 0) ? W2 : (m == 1) ? R1 : R2;
    u16* d = (m == 0) ? Wt2 : (m == 1) ? Rt1 : Rt2;
    d[r] = f2bf(s[k * HID + n]);
  }
}

// ---------------------------------------------------------------------------
// Per-graph CSR build (LDS histogram + shuffle-scan + LDS cursors), one
// 1024-thread block per graph, XCD-swizzled to g%8. CSR record = packed
// dword {src_local:16 | bf16(w):16} -> single 4B store.
// ---------------------------------------------------------------------------
__global__ __launch_bounds__(1024) void build_k(const int* __restrict__ src,
                                                const int* __restrict__ dst,
                                                const float* __restrict__ ew,
                                                int* __restrict__ cin_,
                                                int* __restrict__ cout_,
                                                int* __restrict__ offs,
                                                unsigned* __restrict__ csr) {
  __shared__ int hin[NPG];
  __shared__ int hout[NPG];
  __shared__ int cur[NPG];
  __shared__ int wtot[16];
  int g, part;
  if (!swz(blockIdx.x, 1, g, part)) return;   // grid 8*13 = 104, 4 idle
  const int t = threadIdx.x;
  const int lane = t & 63, wave = t >> 6;
  const int nb = g * NPG, eb = g * EPG;
  if (t < NPG) { hin[t] = 0; hout[t] = 0; }
  __syncthreads();
  for (int e = t; e < EPG; e += 1024) {
    atomicAdd(&hout[src[eb + e] - nb], 1);
    atomicAdd(&hin[dst[eb + e] - nb], 1);
  }
  __syncthreads();
  int v[4];
  int loc = 0;
#pragma unroll
  for (int k = 0; k < 4; ++k) {
    const int idx = t * 4 + k;
    v[k] = (idx < NPG) ? hin[idx] : 0;
    loc += v[k];
  }
  // intra-wave inclusive scan of loc (6 shuffle steps, no barriers)
  int incl = loc;
#pragma unroll
  for (int d = 1; d < 64; d <<= 1) {
    const int x = __shfl_up(incl, d);
    if (lane >= d) incl += x;
  }
  if (lane == 63) wtot[wave] = incl;
  if (t < NPG) { cin_[nb + t] = hin[t]; cout_[nb + t] = hout[t]; }
  __syncthreads();
  int wexc = 0;
  for (int i = 0; i < wave; ++i) wexc += wtot[i];   // broadcast LDS reads
  int run = eb + wexc + (incl - loc);               // exclusive prefix
#pragma unroll
  for (int k = 0; k < 4; ++k) {
    const int idx = t * 4 + k;
    if (idx < NPG) {
      offs[nb + idx] = run;
      cur[idx] = run;
      run += v[k];
    }
  }
  __syncthreads();
  for (int e = t; e < EPG; e += 1024) {
    const int d = dst[eb + e] - nb;
    const int pos = atomicAdd(&cur[d], 1);
    csr[pos] = ((unsigned)(src[eb + e] - nb) << 16) | (unsigned)f2bf(ew[eb + e]);
  }
}

// ---------------------------------------------------------------------------
// Layer-1 GEMM (MFMA bf16), XCD-swizzled, 250-row strips, bf16 output.
// LDS: unpadded rows, 8-bf16 chunks XOR-swizzled by (row & mask).
// A-frag A[m=lane&15][k=quad*8+j]; B-frag B[k=quad*8+j][n=lane&15];
// C/D col=lane&15, row=quad*4+reg (m89-verified).
// ---------------------------------------------------------------------------
__global__ __launch_bounds__(256) void gemm1_k(const float* __restrict__ X,
                                               const u16* __restrict__ Wt,
                                               const int* __restrict__ cout_,
                                               u16* __restrict__ Y) {
  __shared__ u16 Xl[64 * FIN];
  __shared__ u16 Wl[HID * FIN];
  const int tid = threadIdx.x;
  const int wave = tid >> 6, lane = tid & 63, l15 = lane & 15, quad = lane >> 4;
  int g, part;
  if (!swz(blockIdx.x, 4, g, part)) return;
  const int base = g * NPG + part * NSTRIP;

  for (int i = tid; i < HID * (FIN / 8); i += 256) {  // 1024 chunks
    const int n = i >> 3, c = i & 7;
    const short8 w = *(const short8*)(Wt + n * FIN + c * 8);
    *(short8*)&Wl[n * FIN + ((c ^ (n & 7)) << 3)] = w;
  }
  for (int pass = 0; pass < 4; ++pass) {
    __syncthreads();
    for (int i = tid; i < 64 * (FIN / 4); i += 256) {  // 1024
      const int r = i >> 4;
      const int kq = i & 15;
      const int rowi = pass * 64 + r;
      ushort4 u = make_ushort4(0, 0, 0, 0);
      if (rowi < NSTRIP) {
        const float4 x = *(const float4*)(X + (size_t)(base + rowi) * FIN + kq * 4);
        u.x = f2bf(x.x); u.y = f2bf(x.y); u.z = f2bf(x.z); u.w = f2bf(x.w);
      }
      const int c = kq >> 1, half = kq & 1;
      *(ushort4*)&Xl[r * FIN + (((c ^ (r & 7)) << 3) | (half << 2))] = u;
    }
    __syncthreads();
    short8 a[2];
    const int arow = wave * 16 + l15;
#pragma unroll
    for (int kt = 0; kt < 2; ++kt)
      a[kt] = *(const short8*)&Xl[arow * FIN + (((kt * 4 + quad) ^ (l15 & 7)) << 3)];
    float sc[4];
    int rows[4];
#pragma unroll
    for (int r = 0; r < 4; ++r) {
      rows[r] = pass * 64 + wave * 16 + quad * 4 + r;
      sc[r] = (rows[r] < NSTRIP) ? rsqrtf(fmaxf((float)cout_[base + rows[r]], 1.0f)) : 0.f;
    }
#pragma unroll
    for (int ct = 0; ct < 8; ++ct) {
      f32x4 acc = {0.f, 0.f, 0.f, 0.f};
      const int brow = ct * 16 + l15;
#pragma unroll
      for (int kt = 0; kt < 2; ++kt) {
        const short8 b = *(const short8*)&Wl[brow * FIN + (((kt * 4 + quad) ^ (l15 & 7)) << 3)];
        acc = __builtin_amdgcn_mfma_f32_16x16x32_bf16(a[kt], b, acc, 0, 0, 0);
      }
      const int n = ct * 16 + l15;
#pragma unroll
      for (int r = 0; r < 4; ++r)
        if (rows[r] < NSTRIP) Y[(size_t)(base + rows[r]) * HID + n] = f2bf(acc[r] * sc[r]);
    }
  }
}

// ---------------------------------------------------------------------------
// Layer-2 GEMM (MFMA bf16), fused GraphNorm apply, bf16 in/out, XCD-swizzled.
// ---------------------------------------------------------------------------
__global__ __launch_bounds__(256) void gemm_norm_k(const u16* __restrict__ Xb,
                                                   const u16* __restrict__ Wt,
                                                   const float* __restrict__ An,
                                                   const float* __restrict__ Bn,
                                                   const int* __restrict__ cout_,
                                                   u16* __restrict__ Y) {
  __shared__ u16 Xl[64 * HID];
  __shared__ u16 Wl[HID * HID];
  const int tid = threadIdx.x;
  const int wave = tid >> 6, lane = tid & 63, l15 = lane & 15, quad = lane >> 4;
  int g, part;
  if (!swz(blockIdx.x, 4, g, part)) return;
  const int base = g * NPG + part * NSTRIP;

  for (int i = tid; i < HID * (HID / 8); i += 256) {  // 2048 chunks
    const int n = i >> 4, c = i & 15;
    const short8 w = *(const short8*)(Wt + n * HID + c * 8);
    *(short8*)&Wl[n * HID + ((c ^ (n & 15)) << 3)] = w;
  }
  for (int pass = 0; pass < 4; ++pass) {
    __syncthreads();
    for (int i = tid; i < 64 * 16; i += 256) {  // 4 iters, 8 elems each
      const int r = i >> 4;
      const int c8 = i & 15;
      const int rowi = pass * 64 + r;
      short8 o = {0, 0, 0, 0, 0, 0, 0, 0};
      if (rowi < NSTRIP) {
        const int node = base + rowi;
        const short8 xs = *(const short8*)(Xb + (size_t)node * HID + c8 * 8);
        const float4 Aa = *(const float4*)(An + (size_t)g * HID + c8 * 8);
        const float4 Ab = *(const float4*)(An + (size_t)g * HID + c8 * 8 + 4);
        const float4 Ba = *(const float4*)(Bn + (size_t)g * HID + c8 * 8);
        const float4 Bb = *(const float4*)(Bn + (size_t)g * HID + c8 * 8 + 4);
        const float Av[8] = {Aa.x, Aa.y, Aa.z, Aa.w, Ab.x, Ab.y, Ab.z, Ab.w};
        const float Bv[8] = {Ba.x, Ba.y, Ba.z, Ba.w, Bb.x, Bb.y, Bb.z, Bb.w};
#pragma unroll
        for (int j = 0; j < 8; ++j)
          o[j] = (short)f2bf(leaky(fmaf(Av[j], bf2f((u16)xs[j]), Bv[j])));
      }
      *(short8*)&Xl[r * HID + ((c8 ^ (r & 15)) << 3)] = o;
    }
    __syncthreads();
    short8 a[4];
    const int arow = wave * 16 + l15;
#pragma unroll
    for (int kt = 0; kt < 4; ++kt)
      a[kt] = *(const short8*)&Xl[arow * HID + (((kt * 4 + quad) ^ l15) << 3)];
    float sc[4];
    int rows[4];
#pragma unroll
    for (int r = 0; r < 4; ++r) {
      rows[r] = pass * 64 + wave * 16 + quad * 4 + r;
      sc[r] = (rows[r] < NSTRIP) ? rsqrtf(fmaxf((float)cout_[base + rows[r]], 1.0f)) : 0.f;
    }
#pragma unroll
    for (int ct = 0; ct < 8; ++ct) {
      f32x4 acc = {0.f, 0.f, 0.f, 0.f};
      const int brow = ct * 16 + l15;
#pragma unroll
      for (int kt = 0; kt < 4; ++kt) {
        const short8 b = *(const short8*)&Wl[brow * HID + (((kt * 4 + quad) ^ l15) << 3)];
        acc = __builtin_amdgcn_mfma_f32_16x16x32_bf16(a[kt], b, acc, 0, 0, 0);
      }
      const int n = ct * 16 + l15;
#pragma unroll
      for (int r = 0; r < 4; ++r)
        if (rows[r] < NSTRIP) Y[(size_t)(base + rows[r]) * HID + n] = f2bf(acc[r] * sc[r]);
    }
  }
}

// ---------------------------------------------------------------------------
// Readout phi+pool (MFMA bf16), fused norm apply, bf16 input, XCD-swizzled.
// ---------------------------------------------------------------------------
__global__ __launch_bounds__(256) void phi_pool_k(const u16* __restrict__ Xb,
                                                  const float* __restrict__ An,
                                                  const float* __restrict__ Bn,
                                                  const u16* __restrict__ Wt,
                                                  const float* __restrict__ b1,
                                                  float* __restrict__ phi_sum,
                                                  float* __restrict__ h_sum) {
  __shared__ u16 Xl[64 * HID];          // 16 KB
  __shared__ u16 Wl[HID * HID];         // 32 KB
  __shared__ float red[16][HID];        //  8 KB
  __shared__ float hred[16][HID];       //  8 KB  (64 KB total)
  const int tid = threadIdx.x;
  const int wave = tid >> 6, lane = tid & 63, l15 = lane & 15, quad = lane >> 4;
  int g, part;
  if (!swz(blockIdx.x, 4, g, part)) return;
  const int base = g * NPG + part * NSTRIP;

  for (int i = tid; i < HID * (HID / 8); i += 256) {
    const int n = i >> 4, c = i & 15;
    const short8 w = *(const short8*)(Wt + n * HID + c * 8);
    *(short8*)&Wl[n * HID + ((c ^ (n & 15)) << 3)] = w;
  }
  float bcol[8];
#pragma unroll
  for (int ct = 0; ct < 8; ++ct) bcol[ct] = b1[ct * 16 + l15];

  float pooled[8] = {0.f, 0.f, 0.f, 0.f, 0.f, 0.f, 0.f, 0.f};
  float hp[8] = {0.f, 0.f, 0.f, 0.f, 0.f, 0.f, 0.f, 0.f};

  for (int pass = 0; pass < 4; ++pass) {
    __syncthreads();
    for (int i = tid; i < 64 * 16; i += 256) {
      const int r = i >> 4;
      const int c8 = i & 15;   // == tid&15 (stride 256)
      const int rowi = pass * 64 + r;
      short8 o = {0, 0, 0, 0, 0, 0, 0, 0};
      if (rowi < NSTRIP) {
        const int node = base + rowi;
        const short8 xs = *(const short8*)(Xb + (size_t)node * HID + c8 * 8);
        const float4 Aa = *(const float4*)(An + (size_t)g * HID + c8 * 8);
        const float4 Ab = *(const float4*)(An + (size_t)g * HID + c8 * 8 + 4);
        const float4 Ba = *(const float4*)(Bn + (size_t)g * HID + c8 * 8);
        const float4 Bb = *(const float4*)(Bn + (size_t)g * HID + c8 * 8 + 4);
        const float Av[8] = {Aa.x, Aa.y, Aa.z, Aa.w, Ab.x, Ab.y, Ab.z, Ab.w};
        const float Bv[8] = {Ba.x, Ba.y, Ba.z, Ba.w, Bb.x, Bb.y, Bb.z, Bb.w};
#pragma unroll
        for (int j = 0; j < 8; ++j) {
          const float xn = leaky(fmaf(Av[j], bf2f((u16)xs[j]), Bv[j]));
          hp[j] += xn;
          o[j] = (short)f2bf(xn);
        }
      }
      *(short8*)&Xl[r * HID + ((c8 ^ (r & 15)) << 3)] = o;
    }
    __syncthreads();
    short8 a[4];
    const int arow = wave * 16 + l15;
#pragma unroll
    for (int kt = 0; kt < 4; ++kt)
      a[kt] = *(const short8*)&Xl[arow * HID + (((kt * 4 + quad) ^ l15) << 3)];
#pragma unroll
    for (int ct = 0; ct < 8; ++ct) {
      f32x4 acc = {0.f, 0.f, 0.f, 0.f};
      const int brow = ct * 16 + l15;
#pragma unroll
      for (int kt = 0; kt < 4; ++kt) {
        const short8 b = *(const short8*)&Wl[brow * HID + (((kt * 4 + quad) ^ l15) << 3)];
        acc = __builtin_amdgcn_mfma_f32_16x16x32_bf16(a[kt], b, acc, 0, 0, 0);
      }
#pragma unroll
      for (int r = 0; r < 4; ++r) {
        const int rowi = pass * 64 + wave * 16 + quad * 4 + r;
        if (rowi < NSTRIP) pooled[ct] += leaky(acc[r] + bcol[ct]);
      }
    }
  }
  const int qi = wave * 4 + quad;
#pragma unroll
  for (int ct = 0; ct < 8; ++ct) red[qi][ct * 16 + l15] = pooled[ct];
#pragma unroll
  for (int j = 0; j < 8; ++j) hred[tid >> 4][(tid & 15) * 8 + j] = hp[j];
  __syncthreads();
  if (tid < HID) {
    float s = 0.f;
#pragma unroll
    for (int q = 0; q < 16; ++q) s += red[q][tid];
    unsafeAtomicAdd(&phi_sum[g * HID + tid], s);
  } else {
    const int t = tid - HID;
    float s = 0.f;
#pragma unroll
    for (int rr = 0; rr < 16; ++rr) s += hred[rr][t];
    unsafeAtomicAdd(&h_sum[g * HID + t], s);
  }
}

// ---------------------------------------------------------------------------
// Atomic-free aggregation (bf16 in/out) from packed 4B CSR + in_isqrt +
// fused per-graph stats. One coalesced prefetch per 64-edge chunk, then
// 8 edges in flight: 8 shuffles -> 8 loads -> 16 FMAs.
// ---------------------------------------------------------------------------
__global__ __launch_bounds__(256) void gather_k(const u16* __restrict__ H,
                                                const unsigned* __restrict__ csr,
                                                const int* __restrict__ offs,
                                                const int* __restrict__ cin_,
                                                u16* __restrict__ AGG,
                                                float* __restrict__ sx,
                                                float* __restrict__ sq) {
  __shared__ float redx[4][HID];
  __shared__ float redq[4][HID];
  const int wave = threadIdx.x >> 6;
  const int lane = threadIdx.x & 63;
  int g, part;
  if (!swz(blockIdx.x, 25, g, part)) return;
  const int nb = g * NPG;
  const int base = nb + part * GSN;
  const u16* Hg = H + (size_t)nb * HID + lane * 2;  // graph-base row ptr

  float sxa = 0.f, sxb = 0.f, sqa = 0.f, sqb = 0.f;
  for (int n = base + wave; n < base + GSN; n += 4) {
    const int off = offs[n];
    const int cnt = cin_[n];
    const float isq = rsqrtf(fmaxf((float)cnt, 1.0f));
    float ax = 0.f, ay = 0.f, bx = 0.f, by = 0.f;
    int i = 0;
    while (i < cnt) {
      const int take = min(cnt - i, 64);
      unsigned rec = 0;
      if (lane < take) rec = csr[off + i + lane];
      int t = 0;
      for (; t + 8 <= take; t += 8) {
        unsigned r[8];
#pragma unroll
        for (int j = 0; j < 8; ++j) r[j] = (unsigned)__shfl((int)rec, t + j);
        unsigned u[8];
#pragma unroll
        for (int j = 0; j < 8; ++j)
          u[j] = *(const unsigned*)(Hg + (size_t)(r[j] >> 16) * HID);
#pragma unroll
        for (int j = 0; j < 8; ++j) {
          const float w = bf2f((u16)(r[j] & 0xffffu));
          if (j & 1) {
            bx = fmaf(w, __uint_as_float(u[j] << 16), bx);
            by = fmaf(w, __uint_as_float(u[j] & 0xffff0000u), by);
          } else {
            ax = fmaf(w, __uint_as_float(u[j] << 16), ax);
            ay = fmaf(w, __uint_as_float(u[j] & 0xffff0000u), ay);
          }
        }
      }
      for (; t < take; ++t) {
        const unsigned r0 = (unsigned)__shfl((int)rec, t);
        const float w = bf2f((u16)(r0 & 0xffffu));
        const unsigned u0 = *(const unsigned*)(Hg + (size_t)(r0 >> 16) * HID);
        ax = fmaf(w, __uint_as_float(u0 << 16), ax);
        ay = fmaf(w, __uint_as_float(u0 & 0xffff0000u), ay);
      }
      i += take;
    }
    const float rx = (ax + bx) * isq;
    const float ry = (ay + by) * isq;
    const unsigned pk = (unsigned)f2bf(rx) | ((unsigned)f2bf(ry) << 16);
    *(unsigned*)(AGG + (size_t)n * HID + lane * 2) = pk;
    sxa += rx; sxb += ry;
    sqa += rx * rx; sqb += ry * ry;
  }
  redx[wave][lane * 2] = sxa; redx[wave][lane * 2 + 1] = sxb;
  redq[wave][lane * 2] = sqa; redq[wave][lane * 2 + 1] = sqb;
  __syncthreads();
  const int tid = threadIdx.x;
  if (tid < HID) {
    unsafeAtomicAdd(&sx[g * HID + tid],
                    redx[0][tid] + redx[1][tid] + redx[2][tid] + redx[3][tid]);
  } else {
    const int t = tid - HID;
    unsafeAtomicAdd(&sq[g * HID + t],
                    redq[0][t] + redq[1][t] + redq[2][t] + redq[3][t]);
  }
}

// ---------------------------------------------------------------------------
// Fold stats into affine: normalized = A*x + B per (graph, feat).
// ---------------------------------------------------------------------------
__global__ __launch_bounds__(HID) void stats_k(const float* __restrict__ sx,
                                               const float* __restrict__ sq,
                                               const float* __restrict__ alpha,
                                               const float* __restrict__ gamma,
                                               const float* __restrict__ beta,
                                               float* __restrict__ An,
                                               float* __restrict__ Bn) {
  const int g = (blockIdx.x & 7) + 8 * (blockIdx.x >> 3);
  if (g >= NG) return;
  const int j = threadIdx.x;
  const float mean = sx[g * HID + j] * (1.0f / NPG);
  const float ex2 = sq[g * HID + j] * (1.0f / NPG);
  const float am = alpha[j] * mean;
  float var = ex2 - 2.0f * am * mean + am * am;
  var = fmaxf(var, 0.0f);
  const float rstd = rsqrtf(var + EPSV);
  const float A = gamma[j] * rstd;
  An[g * HID + j] = A;
  Bn[g * HID + j] = beta[j] - A * am;
}

// ---------------------------------------------------------------------------
// Readout part 2.
// ---------------------------------------------------------------------------
__global__ __launch_bounds__(64) void finalize_k(const float* __restrict__ phi_sum,
                                                 const float* __restrict__ h_sum,
                                                 const float* __restrict__ w2,
                                                 const float* __restrict__ b2,
                                                 float* __restrict__ out,
                                                 int roff, int moff) {
  const int g = blockIdx.x;
  const int j = threadIdx.x;  // 0..63
  float acc = b2[j];
#pragma unroll 8
  for (int k = 0; k < HID; ++k)
    acc += (phi_sum[g * HID + k] * (1.0f / NPG)) * w2[k * RD + j];
  const float r = leaky(acc);
  out[g * 384 + roff + j] = leaky(r);
  out[g * 384 + moff + j] = leaky(h_sum[g * HID + j] * (1.0f / NPG));
  out[g * 384 + moff + 64 + j] = leaky(h_sum[g * HID + 64 + j] * (1.0f / NPG));
}

// ---------------------------------------------------------------------------
extern "C" void kernel_launch(void* const* d_in, const int* in_sizes, int n_in,
                              void* d_out, int out_size, void* d_ws, size_t ws_size,
                              hipStream_t stream) {
  const float* node_feats = (const float*)d_in[0];
  const float* ew   = (const float*)d_in[1];
  const float* W1   = (const float*)d_in[2];
  const float* W2   = (const float*)d_in[3];
  const float* g1a  = (const float*)d_in[4];
  const float* g1g  = (const float*)d_in[5];
  const float* g1b  = (const float*)d_in[6];
  const float* g2a  = (const float*)d_in[7];
  const float* g2g  = (const float*)d_in[8];
  const float* g2b  = (const float*)d_in[9];
  const float* r1w1 = (const float*)d_in[10];
  const float* r1b1 = (const float*)d_in[11];
  const float* r1w2 = (const float*)d_in[12];
  const float* r1b2 = (const float*)d_in[13];
  const float* r2w1 = (const float*)d_in[14];
  const float* r2b1 = (const float*)d_in[15];
  const float* r2w2 = (const float*)d_in[16];
  const float* r2b2 = (const float*)d_in[17];
  const int* src = (const int*)d_in[18];
  const int* dst = (const int*)d_in[19];
  float* out = (float*)d_out;

  // workspace layout (zeroed region first: phi/h pooled sums + sx/sq)
  char* wsb = (char*)d_ws;
  float* ps1     = (float*)wsb;                       // NG*HID x8, zeroed
  float* hs1     = ps1 + NG * HID;
  float* ps2     = hs1 + NG * HID;
  float* hs2     = ps2 + NG * HID;
  float* sx1     = hs2 + NG * HID;
  float* sq1     = sx1 + NG * HID;
  float* sx2     = sq1 + NG * HID;
  float* sq2     = sx2 + NG * HID;
  int*   cin     = (int*)(sq2 + NG * HID);            // NN (direct store)
  int*   cout_   = cin + NN;                          // NN (direct store)
  int*   offs    = cout_ + NN;                        // NN (direct store)
  unsigned* csr  = (unsigned*)(offs + NN);            // NE packed dwords (6.4 MB)
  float* A1      = (float*)(csr + NE);                // NG*HID x4
  float* B1      = A1 + NG * HID;
  float* A2      = B1 + NG * HID;
  float* B2      = A2 + NG * HID;
  u16*   Wt1     = (u16*)(B2 + NG * HID);             // 128*64
  u16*   Wt2     = Wt1 + HID * FIN;                   // 128*128 x3
  u16*   Rt1     = Wt2 + HID * HID;
  u16*   Rt2     = Rt1 + HID * HID;
  u16*   bufA    = Rt2 + HID * HID;                   // NN*HID bf16
  u16*   bufB    = bufA + (size_t)NN * HID;           // NN*HID bf16

  hipMemsetAsync(d_ws, 0, (size_t)(8 * NG * HID) * sizeof(float), stream);

  // weight transpose + per-graph CSR build (per call)
  wt_k<<<(FIN * HID + 3 * HID * HID) / 256, 256, 0, stream>>>(
      W1, W2, r1w1, r2w1, Wt1, Wt2, Rt1, Rt2);
  build_k<<<8 * 13, 1024, 0, stream>>>(src, dst, ew, cin, cout_, offs, csr);

  const int gemm_grid = 8 * 4 * 13;     // XCD-swizzled, 4 strips/graph
  const int gather_grid = 8 * 25 * 13;  // XCD-swizzled, 25 strips/graph
  const int stats_grid = 8 * 13;

  // ---- layer 1 ----
  gemm1_k<<<gemm_grid, 256, 0, stream>>>(node_feats, Wt1, cout_, bufA);
  gather_k<<<gather_grid, 256, 0, stream>>>(bufA, csr, offs, cin, bufB, sx1, sq1);
  stats_k<<<stats_grid, HID, 0, stream>>>(sx1, sq1, g1a, g1g, g1b, A1, B1);
  phi_pool_k<<<gemm_grid, 256, 0, stream>>>(bufB, A1, B1, Rt1, r1b1, ps1, hs1);
  finalize_k<<<NG, 64, 0, stream>>>(ps1, hs1, r1w2, r1b2, out, 0, 64);

  // ---- layer 2 ----
  gemm_norm_k<<<gemm_grid, 256, 0, stream>>>(bufB, Wt2, A1, B1, cout_, bufA);
  gather_k<<<gather_grid, 256, 0, stream>>>(bufA, csr, offs, cin, bufB, sx2, sq2);
  stats_k<<<stats_grid, HID, 0, stream>>>(sx2, sq2, g2a, g2g, g2b, A2, B2);
  phi_pool_k<<<gemm_grid, 256, 0, stream>>>(bufB, A2, B2, Rt2, r2b1, ps2, hs2);
  finalize_k<<<NG, 64, 0, stream>>>(ps2, hs2, r2w2, r2b2, out, 192, 256);
}

// Round 11
// 334.842 us; speedup vs baseline: 1.0902x; 1.0902x over previous
//
#include <hip/hip_runtime.h>
#include <cstddef>
#include <cstdint>

#define NG   100
#define NPG  1000
#define NN   (NG * NPG)       // 100000 nodes
#define NE   (NN * 16)        // 1600000 edges
#define EPG  (NE / NG)        // 16000 edges per graph (edges are graph-local)
#define CSRG 20000            // CSR capacity/graph (4-aligned segments, 16000+3*1000 max)
#define FIN  64
#define HID  128
#define RD   64
#define SLOPE 0.01f
#define EPSV  1e-5f
#define NSTRIP 250            // nodes per GEMM/phi block (4 strips per graph)
#define GSN   40              // nodes per gather block (25 strips per graph)

using short8 = __attribute__((ext_vector_type(8))) short;   // 8 bf16 = 4 VGPRs
using f32x4  = __attribute__((ext_vector_type(4))) float;
typedef unsigned short u16;

__device__ __forceinline__ float leaky(float x) { return x >= 0.f ? x : SLOPE * x; }

// fp32 -> bf16 (round-to-nearest-even), bit pattern
__device__ __forceinline__ u16 f2bf(float f) {
  union { float f; unsigned u; } v; v.f = f;
  return (u16)((v.u + 0x7fffu + ((v.u >> 16) & 1u)) >> 16);
}
__device__ __forceinline__ float bf2f(u16 u) {
  union { unsigned u; float f; } v; v.u = ((unsigned)u) << 16;
  return v.f;
}

// XCD-affinity swizzle: block->XCD heuristic is blockIdx%8; pin graph g to
// XCD g%8 so producer/consumer blocks of one graph share an L2.
__device__ __forceinline__ bool swz(int b, int per_g, int& g, int& part) {
  const int xcd = b & 7;
  const int slot = b >> 3;
  g = xcd + 8 * (slot / per_g);
  part = slot % per_g;
  return g < NG;
}

// ---------------------------------------------------------------------------
// One-shot bf16 transpose of the four GEMM weight matrices: Wt[n][k]=W[k][n].
// ---------------------------------------------------------------------------
__global__ __launch_bounds__(256) void wt_k(const float* __restrict__ W1,
                                            const float* __restrict__ W2,
                                            const float* __restrict__ R1,
                                            const float* __restrict__ R2,
                                            u16* __restrict__ Wt1,
                                            u16* __restrict__ Wt2,
                                            u16* __restrict__ Rt1,
                                            u16* __restrict__ Rt2) {
  const int idx = blockIdx.x * 256 + threadIdx.x;  // 57344 total
  if (idx < FIN * HID) {
    const int n = idx >> 6, k = idx & 63;          // Wt1 [128][64]
    Wt1[idx] = f2bf(W1[k * HID + n]);
  } else {
    const int j = idx - FIN * HID;
    const int m = j >> 14, r = j & 16383;
    const int n = r >> 7, k = r & 127;
    const float* s = (m == 0) ? W2 : (m == 1) ? R1 : R2;
    u16* d = (m == 0) ? Wt2 : (m == 1) ? Rt1 : Rt2;
    d[r] = f2bf(s[k * HID + n]);
  }
}

// ---------------------------------------------------------------------------
// Per-graph CSR build (LDS histogram + shuffle-scan + LDS cursors), one
// 1024-thread block per graph, XCD-swizzled to g%8. CSR record = packed
// dword {src_local:16 | bf16(w):16}; each node's segment start is padded to
// a multiple of 4 records (16B) so the gather can use s_load_dwordx4.
// ---------------------------------------------------------------------------
__global__ __launch_bounds__(1024) void build_k(const int* __restrict__ src,
                                                const int* __restrict__ dst,
                                                const float* __restrict__ ew,
                                                int* __restrict__ cin_,
                                                int* __restrict__ cout_,
                                                int* __restrict__ offs,
                                                unsigned* __restrict__ csr) {
  __shared__ int hin[NPG];
  __shared__ int hout[NPG];
  __shared__ int cur[NPG];
  __shared__ int wtot[16];
  int g, part;
  if (!swz(blockIdx.x, 1, g, part)) return;   // grid 8*13 = 104, 4 idle
  const int t = threadIdx.x;
  const int lane = t & 63, wave = t >> 6;
  const int nb = g * NPG, eb = g * EPG;
  if (t < NPG) { hin[t] = 0; hout[t] = 0; }
  __syncthreads();
  for (int e = t; e < EPG; e += 1024) {
    atomicAdd(&hout[src[eb + e] - nb], 1);
    atomicAdd(&hin[dst[eb + e] - nb], 1);
  }
  __syncthreads();
  int v[4], vr[4];
  int loc = 0;
#pragma unroll
  for (int k = 0; k < 4; ++k) {
    const int idx = t * 4 + k;
    v[k] = (idx < NPG) ? hin[idx] : 0;
    vr[k] = (v[k] + 3) & ~3;          // 4-record-aligned segment size
    loc += vr[k];
  }
  // intra-wave inclusive scan of loc (6 shuffle steps, no barriers)
  int incl = loc;
#pragma unroll
  for (int d = 1; d < 64; d <<= 1) {
    const int x = __shfl_up(incl, d);
    if (lane >= d) incl += x;
  }
  if (lane == 63) wtot[wave] = incl;
  if (t < NPG) { cin_[nb + t] = hin[t]; cout_[nb + t] = hout[t]; }
  __syncthreads();
  int wexc = 0;
  for (int i = 0; i < wave; ++i) wexc += wtot[i];   // broadcast LDS reads
  int run = g * CSRG + wexc + (incl - loc);         // exclusive prefix, aligned
#pragma unroll
  for (int k = 0; k < 4; ++k) {
    const int idx = t * 4 + k;
    if (idx < NPG) {
      offs[nb + idx] = run;
      cur[idx] = run;
      run += vr[k];
    }
  }
  __syncthreads();
  for (int e = t; e < EPG; e += 1024) {
    const int d = dst[eb + e] - nb;
    const int pos = atomicAdd(&cur[d], 1);
    csr[pos] = ((unsigned)(src[eb + e] - nb) << 16) | (unsigned)f2bf(ew[eb + e]);
  }
}

// ---------------------------------------------------------------------------
// Layer-1 GEMM (MFMA bf16), XCD-swizzled, 250-row strips, bf16 output.
// LDS: unpadded rows, 8-bf16 chunks XOR-swizzled by (row & mask).
// A-frag A[m=lane&15][k=quad*8+j]; B-frag B[k=quad*8+j][n=lane&15];
// C/D col=lane&15, row=quad*4+reg (m89-verified).
// ---------------------------------------------------------------------------
__global__ __launch_bounds__(256) void gemm1_k(const float* __restrict__ X,
                                               const u16* __restrict__ Wt,
                                               const int* __restrict__ cout_,
                                               u16* __restrict__ Y) {
  __shared__ u16 Xl[64 * FIN];
  __shared__ u16 Wl[HID * FIN];
  const int tid = threadIdx.x;
  const int wave = tid >> 6, lane = tid & 63, l15 = lane & 15, quad = lane >> 4;
  int g, part;
  if (!swz(blockIdx.x, 4, g, part)) return;
  const int base = g * NPG + part * NSTRIP;

  for (int i = tid; i < HID * (FIN / 8); i += 256) {  // 1024 chunks
    const int n = i >> 3, c = i & 7;
    const short8 w = *(const short8*)(Wt + n * FIN + c * 8);
    *(short8*)&Wl[n * FIN + ((c ^ (n & 7)) << 3)] = w;
  }
  for (int pass = 0; pass < 4; ++pass) {
    __syncthreads();
    for (int i = tid; i < 64 * (FIN / 4); i += 256) {  // 1024
      const int r = i >> 4;
      const int kq = i & 15;
      const int rowi = pass * 64 + r;
      ushort4 u = make_ushort4(0, 0, 0, 0);
      if (rowi < NSTRIP) {
        const float4 x = *(const float4*)(X + (size_t)(base + rowi) * FIN + kq * 4);
        u.x = f2bf(x.x); u.y = f2bf(x.y); u.z = f2bf(x.z); u.w = f2bf(x.w);
      }
      const int c = kq >> 1, half = kq & 1;
      *(ushort4*)&Xl[r * FIN + (((c ^ (r & 7)) << 3) | (half << 2))] = u;
    }
    __syncthreads();
    short8 a[2];
    const int arow = wave * 16 + l15;
#pragma unroll
    for (int kt = 0; kt < 2; ++kt)
      a[kt] = *(const short8*)&Xl[arow * FIN + (((kt * 4 + quad) ^ (l15 & 7)) << 3)];
    float sc[4];
    int rows[4];
#pragma unroll
    for (int r = 0; r < 4; ++r) {
      rows[r] = pass * 64 + wave * 16 + quad * 4 + r;
      sc[r] = (rows[r] < NSTRIP) ? rsqrtf(fmaxf((float)cout_[base + rows[r]], 1.0f)) : 0.f;
    }
#pragma unroll
    for (int ct = 0; ct < 8; ++ct) {
      f32x4 acc = {0.f, 0.f, 0.f, 0.f};
      const int brow = ct * 16 + l15;
#pragma unroll
      for (int kt = 0; kt < 2; ++kt) {
        const short8 b = *(const short8*)&Wl[brow * FIN + (((kt * 4 + quad) ^ (l15 & 7)) << 3)];
        acc = __builtin_amdgcn_mfma_f32_16x16x32_bf16(a[kt], b, acc, 0, 0, 0);
      }
      const int n = ct * 16 + l15;
#pragma unroll
      for (int r = 0; r < 4; ++r)
        if (rows[r] < NSTRIP) Y[(size_t)(base + rows[r]) * HID + n] = f2bf(acc[r] * sc[r]);
    }
  }
}

// ---------------------------------------------------------------------------
// Layer-2 GEMM (MFMA bf16), fused GraphNorm apply, bf16 in/out, XCD-swizzled.
// ---------------------------------------------------------------------------
__global__ __launch_bounds__(256) void gemm_norm_k(const u16* __restrict__ Xb,
                                                   const u16* __restrict__ Wt,
                                                   const float* __restrict__ An,
                                                   const float* __restrict__ Bn,
                                                   const int* __restrict__ cout_,
                                                   u16* __restrict__ Y) {
  __shared__ u16 Xl[64 * HID];
  __shared__ u16 Wl[HID * HID];
  const int tid = threadIdx.x;
  const int wave = tid >> 6, lane = tid & 63, l15 = lane & 15, quad = lane >> 4;
  int g, part;
  if (!swz(blockIdx.x, 4, g, part)) return;
  const int base = g * NPG + part * NSTRIP;

  for (int i = tid; i < HID * (HID / 8); i += 256) {  // 2048 chunks
    const int n = i >> 4, c = i & 15;
    const short8 w = *(const short8*)(Wt + n * HID + c * 8);
    *(short8*)&Wl[n * HID + ((c ^ (n & 15)) << 3)] = w;
  }
  for (int pass = 0; pass < 4; ++pass) {
    __syncthreads();
    for (int i = tid; i < 64 * 16; i += 256) {  // 4 iters, 8 elems each
      const int r = i >> 4;
      const int c8 = i & 15;
      const int rowi = pass * 64 + r;
      short8 o = {0, 0, 0, 0, 0, 0, 0, 0};
      if (rowi < NSTRIP) {
        const int node = base + rowi;
        const short8 xs = *(const short8*)(Xb + (size_t)node * HID + c8 * 8);
        const float4 Aa = *(const float4*)(An + (size_t)g * HID + c8 * 8);
        const float4 Ab = *(const float4*)(An + (size_t)g * HID + c8 * 8 + 4);
        const float4 Ba = *(const float4*)(Bn + (size_t)g * HID + c8 * 8);
        const float4 Bb = *(const float4*)(Bn + (size_t)g * HID + c8 * 8 + 4);
        const float Av[8] = {Aa.x, Aa.y, Aa.z, Aa.w, Ab.x, Ab.y, Ab.z, Ab.w};
        const float Bv[8] = {Ba.x, Ba.y, Ba.z, Ba.w, Bb.x, Bb.y, Bb.z, Bb.w};
#pragma unroll
        for (int j = 0; j < 8; ++j)
          o[j] = (short)f2bf(leaky(fmaf(Av[j], bf2f((u16)xs[j]), Bv[j])));
      }
      *(short8*)&Xl[r * HID + ((c8 ^ (r & 15)) << 3)] = o;
    }
    __syncthreads();
    short8 a[4];
    const int arow = wave * 16 + l15;
#pragma unroll
    for (int kt = 0; kt < 4; ++kt)
      a[kt] = *(const short8*)&Xl[arow * HID + (((kt * 4 + quad) ^ l15) << 3)];
    float sc[4];
    int rows[4];
#pragma unroll
    for (int r = 0; r < 4; ++r) {
      rows[r] = pass * 64 + wave * 16 + quad * 4 + r;
      sc[r] = (rows[r] < NSTRIP) ? rsqrtf(fmaxf((float)cout_[base + rows[r]], 1.0f)) : 0.f;
    }
#pragma unroll
    for (int ct = 0; ct < 8; ++ct) {
      f32x4 acc = {0.f, 0.f, 0.f, 0.f};
      const int brow = ct * 16 + l15;
#pragma unroll
      for (int kt = 0; kt < 4; ++kt) {
        const short8 b = *(const short8*)&Wl[brow * HID + (((kt * 4 + quad) ^ l15) << 3)];
        acc = __builtin_amdgcn_mfma_f32_16x16x32_bf16(a[kt], b, acc, 0, 0, 0);
      }
      const int n = ct * 16 + l15;
#pragma unroll
      for (int r = 0; r < 4; ++r)
        if (rows[r] < NSTRIP) Y[(size_t)(base + rows[r]) * HID + n] = f2bf(acc[r] * sc[r]);
    }
  }
}

// ---------------------------------------------------------------------------
// Readout phi+pool (MFMA bf16), fused norm apply, bf16 input, XCD-swizzled.
// ---------------------------------------------------------------------------
__global__ __launch_bounds__(256) void phi_pool_k(const u16* __restrict__ Xb,
                                                  const float* __restrict__ An,
                                                  const float* __restrict__ Bn,
                                                  const u16* __restrict__ Wt,
                                                  const float* __restrict__ b1,
                                                  float* __restrict__ phi_sum,
                                                  float* __restrict__ h_sum) {
  __shared__ u16 Xl[64 * HID];          // 16 KB
  __shared__ u16 Wl[HID * HID];         // 32 KB
  __shared__ float red[16][HID];        //  8 KB
  __shared__ float hred[16][HID];       //  8 KB  (64 KB total)
  const int tid = threadIdx.x;
  const int wave = tid >> 6, lane = tid & 63, l15 = lane & 15, quad = lane >> 4;
  int g, part;
  if (!swz(blockIdx.x, 4, g, part)) return;
  const int base = g * NPG + part * NSTRIP;

  for (int i = tid; i < HID * (HID / 8); i += 256) {
    const int n = i >> 4, c = i & 15;
    const short8 w = *(const short8*)(Wt + n * HID + c * 8);
    *(short8*)&Wl[n * HID + ((c ^ (n & 15)) << 3)] = w;
  }
  float bcol[8];
#pragma unroll
  for (int ct = 0; ct < 8; ++ct) bcol[ct] = b1[ct * 16 + l15];

  float pooled[8] = {0.f, 0.f, 0.f, 0.f, 0.f, 0.f, 0.f, 0.f};
  float hp[8] = {0.f, 0.f, 0.f, 0.f, 0.f, 0.f, 0.f, 0.f};

  for (int pass = 0; pass < 4; ++pass) {
    __syncthreads();
    for (int i = tid; i < 64 * 16; i += 256) {
      const int r = i >> 4;
      const int c8 = i & 15;   // == tid&15 (stride 256)
      const int rowi = pass * 64 + r;
      short8 o = {0, 0, 0, 0, 0, 0, 0, 0};
      if (rowi < NSTRIP) {
        const int node = base + rowi;
        const short8 xs = *(const short8*)(Xb + (size_t)node * HID + c8 * 8);
        const float4 Aa = *(const float4*)(An + (size_t)g * HID + c8 * 8);
        const float4 Ab = *(const float4*)(An + (size_t)g * HID + c8 * 8 + 4);
        const float4 Ba = *(const float4*)(Bn + (size_t)g * HID + c8 * 8);
        const float4 Bb = *(const float4*)(Bn + (size_t)g * HID + c8 * 8 + 4);
        const float Av[8] = {Aa.x, Aa.y, Aa.z, Aa.w, Ab.x, Ab.y, Ab.z, Ab.w};
        const float Bv[8] = {Ba.x, Ba.y, Ba.z, Ba.w, Bb.x, Bb.y, Bb.z, Bb.w};
#pragma unroll
        for (int j = 0; j < 8; ++j) {
          const float xn = leaky(fmaf(Av[j], bf2f((u16)xs[j]), Bv[j]));
          hp[j] += xn;
          o[j] = (short)f2bf(xn);
        }
      }
      *(short8*)&Xl[r * HID + ((c8 ^ (r & 15)) << 3)] = o;
    }
    __syncthreads();
    short8 a[4];
    const int arow = wave * 16 + l15;
#pragma unroll
    for (int kt = 0; kt < 4; ++kt)
      a[kt] = *(const short8*)&Xl[arow * HID + (((kt * 4 + quad) ^ l15) << 3)];
#pragma unroll
    for (int ct = 0; ct < 8; ++ct) {
      f32x4 acc = {0.f, 0.f, 0.f, 0.f};
      const int brow = ct * 16 + l15;
#pragma unroll
      for (int kt = 0; kt < 4; ++kt) {
        const short8 b = *(const short8*)&Wl[brow * HID + (((kt * 4 + quad) ^ l15) << 3)];
        acc = __builtin_amdgcn_mfma_f32_16x16x32_bf16(a[kt], b, acc, 0, 0, 0);
      }
#pragma unroll
      for (int r = 0; r < 4; ++r) {
        const int rowi = pass * 64 + wave * 16 + quad * 4 + r;
        if (rowi < NSTRIP) pooled[ct] += leaky(acc[r] + bcol[ct]);
      }
    }
  }
  const int qi = wave * 4 + quad;
#pragma unroll
  for (int ct = 0; ct < 8; ++ct) red[qi][ct * 16 + l15] = pooled[ct];
#pragma unroll
  for (int j = 0; j < 8; ++j) hred[tid >> 4][(tid & 15) * 8 + j] = hp[j];
  __syncthreads();
  if (tid < HID) {
    float s = 0.f;
#pragma unroll
    for (int q = 0; q < 16; ++q) s += red[q][tid];
    unsafeAtomicAdd(&phi_sum[g * HID + tid], s);
  } else {
    const int t = tid - HID;
    float s = 0.f;
#pragma unroll
    for (int rr = 0; rr < 16; ++rr) s += hred[rr][t];
    unsafeAtomicAdd(&h_sum[g * HID + t], s);
  }
}

// ---------------------------------------------------------------------------
// Atomic-free aggregation (bf16 in/out), SCALAR-PIPE edge records: node
// index/offset/count forced wave-uniform (readfirstlane) so CSR records load
// via s_load_dwordx4 (16B-aligned segments) and each H row base is an SGPR
// pair -> saddr-form global_load with zero VALU address math. Per-edge VALU:
// 1 unpack + 2 FMA.
// ---------------------------------------------------------------------------
__global__ __launch_bounds__(256) void gather_k(const u16* __restrict__ H,
                                                const unsigned* __restrict__ csr,
                                                const int* __restrict__ offs,
                                                const int* __restrict__ cin_,
                                                u16* __restrict__ AGG,
                                                float* __restrict__ sx,
                                                float* __restrict__ sq) {
  __shared__ float redx[4][HID];
  __shared__ float redq[4][HID];
  const int wave = threadIdx.x >> 6;
  const int lane = threadIdx.x & 63;
  int g, part;
  if (!swz(blockIdx.x, 25, g, part)) return;
  const int nb = g * NPG;
  const int base = nb + part * GSN;
  const int loff = lane * 2;
  const u16* __restrict__ Hg = H + (size_t)nb * HID;

  float sxa = 0.f, sxb = 0.f, sqa = 0.f, sqb = 0.f;
  for (int n0 = wave; n0 < GSN; n0 += 4) {
    const int n = base + n0;
    const int nu = __builtin_amdgcn_readfirstlane(n);
    const int off = __builtin_amdgcn_readfirstlane(offs[nu]);
    const int cnt = __builtin_amdgcn_readfirstlane(cin_[nu]);
    const float isq = rsqrtf(fmaxf((float)cnt, 1.0f));
    const uint4* __restrict__ cp4 =
        (const uint4*)__builtin_assume_aligned(csr + off, 16);
    float ax = 0.f, ay = 0.f, bx = 0.f, by = 0.f;
    const int n4 = cnt >> 2;
    for (int t4 = 0; t4 < n4; ++t4) {
      const uint4 rv = cp4[t4];                       // s_load_dwordx4
      const unsigned u0 = *(const unsigned*)(Hg + (size_t)(rv.x >> 16) * HID + loff);
      const unsigned u1 = *(const unsigned*)(Hg + (size_t)(rv.y >> 16) * HID + loff);
      const unsigned u2 = *(const unsigned*)(Hg + (size_t)(rv.z >> 16) * HID + loff);
      const unsigned u3 = *(const unsigned*)(Hg + (size_t)(rv.w >> 16) * HID + loff);
      const float w0 = bf2f((u16)(rv.x & 0xffffu));   // scalar shifts, SGPR src
      const float w1 = bf2f((u16)(rv.y & 0xffffu));
      const float w2 = bf2f((u16)(rv.z & 0xffffu));
      const float w3 = bf2f((u16)(rv.w & 0xffffu));
      ax = fmaf(w0, __uint_as_float(u0 << 16), ax);
      ay = fmaf(w0, __uint_as_float(u0 & 0xffff0000u), ay);
      bx = fmaf(w1, __uint_as_float(u1 << 16), bx);
      by = fmaf(w1, __uint_as_float(u1 & 0xffff0000u), by);
      ax = fmaf(w2, __uint_as_float(u2 << 16), ax);
      ay = fmaf(w2, __uint_as_float(u2 & 0xffff0000u), ay);
      bx = fmaf(w3, __uint_as_float(u3 << 16), bx);
      by = fmaf(w3, __uint_as_float(u3 & 0xffff0000u), by);
    }
    for (int t = n4 << 2; t < cnt; ++t) {
      const unsigned r0 = csr[off + t];               // uniform s_load
      const float w = bf2f((u16)(r0 & 0xffffu));
      const unsigned u0 = *(const unsigned*)(Hg + (size_t)(r0 >> 16) * HID + loff);
      ax = fmaf(w, __uint_as_float(u0 << 16), ax);
      ay = fmaf(w, __uint_as_float(u0 & 0xffff0000u), ay);
    }
    const float rx = (ax + bx) * isq;
    const float ry = (ay + by) * isq;
    const unsigned pk = (unsigned)f2bf(rx) | ((unsigned)f2bf(ry) << 16);
    *(unsigned*)(AGG + (size_t)n * HID + loff) = pk;
    sxa += rx; sxb += ry;
    sqa += rx * rx; sqb += ry * ry;
  }
  redx[wave][loff] = sxa; redx[wave][loff + 1] = sxb;
  redq[wave][loff] = sqa; redq[wave][loff + 1] = sqb;
  __syncthreads();
  const int tid = threadIdx.x;
  if (tid < HID) {
    unsafeAtomicAdd(&sx[g * HID + tid],
                    redx[0][tid] + redx[1][tid] + redx[2][tid] + redx[3][tid]);
  } else {
    const int t = tid - HID;
    unsafeAtomicAdd(&sq[g * HID + t],
                    redq[0][t] + redq[1][t] + redq[2][t] + redq[3][t]);
  }
}

// ---------------------------------------------------------------------------
// Fold stats into affine: normalized = A*x + B per (graph, feat).
// ---------------------------------------------------------------------------
__global__ __launch_bounds__(HID) void stats_k(const float* __restrict__ sx,
                                               const float* __restrict__ sq,
                                               const float* __restrict__ alpha,
                                               const float* __restrict__ gamma,
                                               const float* __restrict__ beta,
                                               float* __restrict__ An,
                                               float* __restrict__ Bn) {
  const int g = (blockIdx.x & 7) + 8 * (blockIdx.x >> 3);
  if (g >= NG) return;
  const int j = threadIdx.x;
  const float mean = sx[g * HID + j] * (1.0f / NPG);
  const float ex2 = sq[g * HID + j] * (1.0f / NPG);
  const float am = alpha[j] * mean;
  float var = ex2 - 2.0f * am * mean + am * am;
  var = fmaxf(var, 0.0f);
  const float rstd = rsqrtf(var + EPSV);
  const float A = gamma[j] * rstd;
  An[g * HID + j] = A;
  Bn[g * HID + j] = beta[j] - A * am;
}

// ---------------------------------------------------------------------------
// Readout part 2.
// ---------------------------------------------------------------------------
__global__ __launch_bounds__(64) void finalize_k(const float* __restrict__ phi_sum,
                                                 const float* __restrict__ h_sum,
                                                 const float* __restrict__ w2,
                                                 const float* __restrict__ b2,
                                                 float* __restrict__ out,
                                                 int roff, int moff) {
  const int g = blockIdx.x;
  const int j = threadIdx.x;  // 0..63
  float acc = b2[j];
#pragma unroll 8
  for (int k = 0; k < HID; ++k)
    acc += (phi_sum[g * HID + k] * (1.0f / NPG)) * w2[k * RD + j];
  const float r = leaky(acc);
  out[g * 384 + roff + j] = leaky(r);
  out[g * 384 + moff + j] = leaky(h_sum[g * HID + j] * (1.0f / NPG));
  out[g * 384 + moff + 64 + j] = leaky(h_sum[g * HID + 64 + j] * (1.0f / NPG));
}

// ---------------------------------------------------------------------------
extern "C" void kernel_launch(void* const* d_in, const int* in_sizes, int n_in,
                              void* d_out, int out_size, void* d_ws, size_t ws_size,
                              hipStream_t stream) {
  const float* node_feats = (const float*)d_in[0];
  const float* ew   = (const float*)d_in[1];
  const float* W1   = (const float*)d_in[2];
  const float* W2   = (const float*)d_in[3];
  const float* g1a  = (const float*)d_in[4];
  const float* g1g  = (const float*)d_in[5];
  const float* g1b  = (const float*)d_in[6];
  const float* g2a  = (const float*)d_in[7];
  const float* g2g  = (const float*)d_in[8];
  const float* g2b  = (const float*)d_in[9];
  const float* r1w1 = (const float*)d_in[10];
  const float* r1b1 = (const float*)d_in[11];
  const float* r1w2 = (const float*)d_in[12];
  const float* r1b2 = (const float*)d_in[13];
  const float* r2w1 = (const float*)d_in[14];
  const float* r2b1 = (const float*)d_in[15];
  const float* r2w2 = (const float*)d_in[16];
  const float* r2b2 = (const float*)d_in[17];
  const int* src = (const int*)d_in[18];
  const int* dst = (const int*)d_in[19];
  float* out = (float*)d_out;

  // workspace layout (zeroed region first: phi/h pooled sums + sx/sq)
  char* wsb = (char*)d_ws;
  float* ps1     = (float*)wsb;                       // NG*HID x8, zeroed
  float* hs1     = ps1 + NG * HID;
  float* ps2     = hs1 + NG * HID;
  float* hs2     = ps2 + NG * HID;
  float* sx1     = hs2 + NG * HID;
  float* sq1     = sx1 + NG * HID;
  float* sx2     = sq1 + NG * HID;
  float* sq2     = sx2 + NG * HID;
  int*   cin     = (int*)(sq2 + NG * HID);            // NN (direct store)
  int*   cout_   = cin + NN;                          // NN (direct store)
  int*   offs    = cout_ + NN;                        // NN (direct store)
  unsigned* csr  = (unsigned*)(offs + NN);            // NG*CSRG packed dwords (8 MB)
  float* A1      = (float*)(csr + (size_t)NG * CSRG); // NG*HID x4
  float* B1      = A1 + NG * HID;
  float* A2      = B1 + NG * HID;
  float* B2      = A2 + NG * HID;
  u16*   Wt1     = (u16*)(B2 + NG * HID);             // 128*64
  u16*   Wt2     = Wt1 + HID * FIN;                   // 128*128 x3
  u16*   Rt1     = Wt2 + HID * HID;
  u16*   Rt2     = Rt1 + HID * HID;
  u16*   bufA    = Rt2 + HID * HID;                   // NN*HID bf16
  u16*   bufB    = bufA + (size_t)NN * HID;           // NN*HID bf16

  hipMemsetAsync(d_ws, 0, (size_t)(8 * NG * HID) * sizeof(float), stream);

  // weight transpose + per-graph CSR build (per call)
  wt_k<<<(FIN * HID + 3 * HID * HID) / 256, 256, 0, stream>>>(
      W1, W2, r1w1, r2w1, Wt1, Wt2, Rt1, Rt2);
  build_k<<<8 * 13, 1024, 0, stream>>>(src, dst, ew, cin, cout_, offs, csr);

  const int gemm_grid = 8 * 4 * 13;     // XCD-swizzled, 4 strips/graph
  const int gather_grid = 8 * 25 * 13;  // XCD-swizzled, 25 strips/graph
  const int stats_grid = 8 * 13;

  // ---- layer 1 ----
  gemm1_k<<<gemm_grid, 256, 0, stream>>>(node_feats, Wt1, cout_, bufA);
  gather_k<<<gather_grid, 256, 0, stream>>>(bufA, csr, offs, cin, bufB, sx1, sq1);
  stats_k<<<stats_grid, HID, 0, stream>>>(sx1, sq1, g1a, g1g, g1b, A1, B1);
  phi_pool_k<<<gemm_grid, 256, 0, stream>>>(bufB, A1, B1, Rt1, r1b1, ps1, hs1);
  finalize_k<<<NG, 64, 0, stream>>>(ps1, hs1, r1w2, r1b2, out, 0, 64);

  // ---- layer 2 ----
  gemm_norm_k<<<gemm_grid, 256, 0, stream>>>(bufB, Wt2, A1, B1, cout_, bufA);
  gather_k<<<gather_grid, 256, 0, stream>>>(bufA, csr, offs, cin, bufB, sx2, sq2);
  stats_k<<<stats_grid, HID, 0, stream>>>(sx2, sq2, g2a, g2g, g2b, A2, B2);
  phi_pool_k<<<gemm_grid, 256, 0, stream>>>(bufB, A2, B2, Rt2, r2b1, ps2, hs2);
  finalize_k<<<NG, 64, 0, stream>>>(ps2, hs2, r2w2, r2b2, out, 192, 256);
}

// Round 12
// 319.347 us; speedup vs baseline: 1.1431x; 1.0485x over previous
//
#include <hip/hip_runtime.h>
#include <cstddef>
#include <cstdint>

#define NG   100
#define NPG  1000
#define NN   (NG * NPG)       // 100000 nodes
#define NE   (NN * 16)        // 1600000 edges
#define EPG  (NE / NG)        // 16000 edges per graph (edges are graph-local)
#define CSRG 20000            // CSR capacity/graph (4-aligned segments)
#define FIN  64
#define HID  128
#define RD   64
#define SLOPE 0.01f
#define EPSV  1e-5f
#define NSTRIP 250            // nodes per GEMM/phi block (4 strips per graph)
#define GSN   40              // nodes per gather block (25 strips per graph)

using short8 = __attribute__((ext_vector_type(8))) short;   // 8 bf16 = 4 VGPRs
using f32x4  = __attribute__((ext_vector_type(4))) float;
typedef unsigned short u16;

__device__ __forceinline__ float leaky(float x) { return x >= 0.f ? x : SLOPE * x; }

// fp32 -> bf16 (round-to-nearest-even), bit pattern
__device__ __forceinline__ u16 f2bf(float f) {
  union { float f; unsigned u; } v; v.f = f;
  return (u16)((v.u + 0x7fffu + ((v.u >> 16) & 1u)) >> 16);
}
__device__ __forceinline__ float bf2f(u16 u) {
  union { unsigned u; float f; } v; v.u = ((unsigned)u) << 16;
  return v.f;
}

// XCD-affinity swizzle: block->XCD heuristic is blockIdx%8; pin graph g to
// XCD g%8 so producer/consumer blocks of one graph share an L2.
__device__ __forceinline__ bool swz(int b, int per_g, int& g, int& part) {
  const int xcd = b & 7;
  const int slot = b >> 3;
  g = xcd + 8 * (slot / per_g);
  part = slot % per_g;
  return g < NG;
}

// ---------------------------------------------------------------------------
// One-shot bf16 transpose of the four GEMM weight matrices: Wt[n][k]=W[k][n].
// ---------------------------------------------------------------------------
__global__ __launch_bounds__(256) void wt_k(const float* __restrict__ W1,
                                            const float* __restrict__ W2,
                                            const float* __restrict__ R1,
                                            const float* __restrict__ R2,
                                            u16* __restrict__ Wt1,
                                            u16* __restrict__ Wt2,
                                            u16* __restrict__ Rt1,
                                            u16* __restrict__ Rt2) {
  const int idx = blockIdx.x * 256 + threadIdx.x;  // 57344 total
  if (idx < FIN * HID) {
    const int n = idx >> 6, k = idx & 63;          // Wt1 [128][64]
    Wt1[idx] = f2bf(W1[k * HID + n]);
  } else {
    const int j = idx - FIN * HID;
    const int m = j >> 14, r = j & 16383;
    const int n = r >> 7, k = r & 127;
    const float* s = (m == 0) ? W2 : (m == 1) ? R1 : R2;
    u16* d = (m == 0) ? Wt2 : (m == 1) ? Rt1 : Rt2;
    d[r] = f2bf(s[k * HID + n]);
  }
}

// ---------------------------------------------------------------------------
// Per-graph CSR build (LDS histogram + shuffle-scan + LDS cursors), one
// 1024-thread block per graph, XCD-swizzled to g%8. CSR record = packed
// dword {src_local:16 | bf16(w):16}; each node's segment start is padded to
// a multiple of 4 records (16B) so the gather can use s_load_dwordx4.
// ---------------------------------------------------------------------------
__global__ __launch_bounds__(1024) void build_k(const int* __restrict__ src,
                                                const int* __restrict__ dst,
                                                const float* __restrict__ ew,
                                                int* __restrict__ cin_,
                                                int* __restrict__ cout_,
                                                int* __restrict__ offs,
                                                unsigned* __restrict__ csr) {
  __shared__ int hin[NPG];
  __shared__ int hout[NPG];
  __shared__ int cur[NPG];
  __shared__ int wtot[16];
  int g, part;
  if (!swz(blockIdx.x, 1, g, part)) return;   // grid 8*13 = 104, 4 idle
  const int t = threadIdx.x;
  const int lane = t & 63, wave = t >> 6;
  const int nb = g * NPG, eb = g * EPG;
  if (t < NPG) { hin[t] = 0; hout[t] = 0; }
  __syncthreads();
  for (int e = t; e < EPG; e += 1024) {
    atomicAdd(&hout[src[eb + e] - nb], 1);
    atomicAdd(&hin[dst[eb + e] - nb], 1);
  }
  __syncthreads();
  int v[4], vr[4];
  int loc = 0;
#pragma unroll
  for (int k = 0; k < 4; ++k) {
    const int idx = t * 4 + k;
    v[k] = (idx < NPG) ? hin[idx] : 0;
    vr[k] = (v[k] + 3) & ~3;          // 4-record-aligned segment size
    loc += vr[k];
  }
  // intra-wave inclusive scan of loc (6 shuffle steps, no barriers)
  int incl = loc;
#pragma unroll
  for (int d = 1; d < 64; d <<= 1) {
    const int x = __shfl_up(incl, d);
    if (lane >= d) incl += x;
  }
  if (lane == 63) wtot[wave] = incl;
  if (t < NPG) { cin_[nb + t] = hin[t]; cout_[nb + t] = hout[t]; }
  __syncthreads();
  int wexc = 0;
  for (int i = 0; i < wave; ++i) wexc += wtot[i];   // broadcast LDS reads
  int run = g * CSRG + wexc + (incl - loc);         // exclusive prefix, aligned
#pragma unroll
  for (int k = 0; k < 4; ++k) {
    const int idx = t * 4 + k;
    if (idx < NPG) {
      offs[nb + idx] = run;
      cur[idx] = run;
      run += vr[k];
    }
  }
  __syncthreads();
  for (int e = t; e < EPG; e += 1024) {
    const int d = dst[eb + e] - nb;
    const int pos = atomicAdd(&cur[d], 1);
    csr[pos] = ((unsigned)(src[eb + e] - nb) << 16) | (unsigned)f2bf(ew[eb + e]);
  }
}

// ---------------------------------------------------------------------------
// Layer-1 GEMM (MFMA bf16), XCD-swizzled, 250-row strips, bf16 output.
// ---------------------------------------------------------------------------
__global__ __launch_bounds__(256) void gemm1_k(const float* __restrict__ X,
                                               const u16* __restrict__ Wt,
                                               const int* __restrict__ cout_,
                                               u16* __restrict__ Y) {
  __shared__ u16 Xl[64 * FIN];
  __shared__ u16 Wl[HID * FIN];
  const int tid = threadIdx.x;
  const int wave = tid >> 6, lane = tid & 63, l15 = lane & 15, quad = lane >> 4;
  int g, part;
  if (!swz(blockIdx.x, 4, g, part)) return;
  const int base = g * NPG + part * NSTRIP;

  for (int i = tid; i < HID * (FIN / 8); i += 256) {  // 1024 chunks
    const int n = i >> 3, c = i & 7;
    const short8 w = *(const short8*)(Wt + n * FIN + c * 8);
    *(short8*)&Wl[n * FIN + ((c ^ (n & 7)) << 3)] = w;
  }
  for (int pass = 0; pass < 4; ++pass) {
    __syncthreads();
    for (int i = tid; i < 64 * (FIN / 4); i += 256) {  // 1024
      const int r = i >> 4;
      const int kq = i & 15;
      const int rowi = pass * 64 + r;
      ushort4 u = make_ushort4(0, 0, 0, 0);
      if (rowi < NSTRIP) {
        const float4 x = *(const float4*)(X + (size_t)(base + rowi) * FIN + kq * 4);
        u.x = f2bf(x.x); u.y = f2bf(x.y); u.z = f2bf(x.z); u.w = f2bf(x.w);
      }
      const int c = kq >> 1, half = kq & 1;
      *(ushort4*)&Xl[r * FIN + (((c ^ (r & 7)) << 3) | (half << 2))] = u;
    }
    __syncthreads();
    short8 a[2];
    const int arow = wave * 16 + l15;
#pragma unroll
    for (int kt = 0; kt < 2; ++kt)
      a[kt] = *(const short8*)&Xl[arow * FIN + (((kt * 4 + quad) ^ (l15 & 7)) << 3)];
    float sc[4];
    int rows[4];
#pragma unroll
    for (int r = 0; r < 4; ++r) {
      rows[r] = pass * 64 + wave * 16 + quad * 4 + r;
      sc[r] = (rows[r] < NSTRIP) ? rsqrtf(fmaxf((float)cout_[base + rows[r]], 1.0f)) : 0.f;
    }
#pragma unroll
    for (int ct = 0; ct < 8; ++ct) {
      f32x4 acc = {0.f, 0.f, 0.f, 0.f};
      const int brow = ct * 16 + l15;
#pragma unroll
      for (int kt = 0; kt < 2; ++kt) {
        const short8 b = *(const short8*)&Wl[brow * FIN + (((kt * 4 + quad) ^ (l15 & 7)) << 3)];
        acc = __builtin_amdgcn_mfma_f32_16x16x32_bf16(a[kt], b, acc, 0, 0, 0);
      }
      const int n = ct * 16 + l15;
#pragma unroll
      for (int r = 0; r < 4; ++r)
        if (rows[r] < NSTRIP) Y[(size_t)(base + rows[r]) * HID + n] = f2bf(acc[r] * sc[r]);
    }
  }
}

// ---------------------------------------------------------------------------
// Layer-2 GEMM (MFMA bf16), fused GraphNorm apply, bf16 in/out, XCD-swizzled.
// ---------------------------------------------------------------------------
__global__ __launch_bounds__(256) void gemm_norm_k(const u16* __restrict__ Xb,
                                                   const u16* __restrict__ Wt,
                                                   const float* __restrict__ An,
                                                   const float* __restrict__ Bn,
                                                   const int* __restrict__ cout_,
                                                   u16* __restrict__ Y) {
  __shared__ u16 Xl[64 * HID];
  __shared__ u16 Wl[HID * HID];
  const int tid = threadIdx.x;
  const int wave = tid >> 6, lane = tid & 63, l15 = lane & 15, quad = lane >> 4;
  int g, part;
  if (!swz(blockIdx.x, 4, g, part)) return;
  const int base = g * NPG + part * NSTRIP;

  for (int i = tid; i < HID * (HID / 8); i += 256) {  // 2048 chunks
    const int n = i >> 4, c = i & 15;
    const short8 w = *(const short8*)(Wt + n * HID + c * 8);
    *(short8*)&Wl[n * HID + ((c ^ (n & 15)) << 3)] = w;
  }
  for (int pass = 0; pass < 4; ++pass) {
    __syncthreads();
    for (int i = tid; i < 64 * 16; i += 256) {  // 4 iters, 8 elems each
      const int r = i >> 4;
      const int c8 = i & 15;
      const int rowi = pass * 64 + r;
      short8 o = {0, 0, 0, 0, 0, 0, 0, 0};
      if (rowi < NSTRIP) {
        const int node = base + rowi;
        const short8 xs = *(const short8*)(Xb + (size_t)node * HID + c8 * 8);
        const float4 Aa = *(const float4*)(An + (size_t)g * HID + c8 * 8);
        const float4 Ab = *(const float4*)(An + (size_t)g * HID + c8 * 8 + 4);
        const float4 Ba = *(const float4*)(Bn + (size_t)g * HID + c8 * 8);
        const float4 Bb = *(const float4*)(Bn + (size_t)g * HID + c8 * 8 + 4);
        const float Av[8] = {Aa.x, Aa.y, Aa.z, Aa.w, Ab.x, Ab.y, Ab.z, Ab.w};
        const float Bv[8] = {Ba.x, Ba.y, Ba.z, Ba.w, Bb.x, Bb.y, Bb.z, Bb.w};
#pragma unroll
        for (int j = 0; j < 8; ++j)
          o[j] = (short)f2bf(leaky(fmaf(Av[j], bf2f((u16)xs[j]), Bv[j])));
      }
      *(short8*)&Xl[r * HID + ((c8 ^ (r & 15)) << 3)] = o;
    }
    __syncthreads();
    short8 a[4];
    const int arow = wave * 16 + l15;
#pragma unroll
    for (int kt = 0; kt < 4; ++kt)
      a[kt] = *(const short8*)&Xl[arow * HID + (((kt * 4 + quad) ^ l15) << 3)];
    float sc[4];
    int rows[4];
#pragma unroll
    for (int r = 0; r < 4; ++r) {
      rows[r] = pass * 64 + wave * 16 + quad * 4 + r;
      sc[r] = (rows[r] < NSTRIP) ? rsqrtf(fmaxf((float)cout_[base + rows[r]], 1.0f)) : 0.f;
    }
#pragma unroll
    for (int ct = 0; ct < 8; ++ct) {
      f32x4 acc = {0.f, 0.f, 0.f, 0.f};
      const int brow = ct * 16 + l15;
#pragma unroll
      for (int kt = 0; kt < 4; ++kt) {
        const short8 b = *(const short8*)&Wl[brow * HID + (((kt * 4 + quad) ^ l15) << 3)];
        acc = __builtin_amdgcn_mfma_f32_16x16x32_bf16(a[kt], b, acc, 0, 0, 0);
      }
      const int n = ct * 16 + l15;
#pragma unroll
      for (int r = 0; r < 4; ++r)
        if (rows[r] < NSTRIP) Y[(size_t)(base + rows[r]) * HID + n] = f2bf(acc[r] * sc[r]);
    }
  }
}

// ---------------------------------------------------------------------------
// Readout phi+pool (MFMA bf16), fused norm apply, bf16 input, XCD-swizzled.
// ---------------------------------------------------------------------------
__global__ __launch_bounds__(256) void phi_pool_k(const u16* __restrict__ Xb,
                                                  const float* __restrict__ An,
                                                  const float* __restrict__ Bn,
                                                  const u16* __restrict__ Wt,
                                                  const float* __restrict__ b1,
                                                  float* __restrict__ phi_sum,
                                                  float* __restrict__ h_sum) {
  __shared__ u16 Xl[64 * HID];          // 16 KB
  __shared__ u16 Wl[HID * HID];         // 32 KB
  __shared__ float red[16][HID];        //  8 KB
  __shared__ float hred[16][HID];       //  8 KB  (64 KB total)
  const int tid = threadIdx.x;
  const int wave = tid >> 6, lane = tid & 63, l15 = lane & 15, quad = lane >> 4;
  int g, part;
  if (!swz(blockIdx.x, 4, g, part)) return;
  const int base = g * NPG + part * NSTRIP;

  for (int i = tid; i < HID * (HID / 8); i += 256) {
    const int n = i >> 4, c = i & 15;
    const short8 w = *(const short8*)(Wt + n * HID + c * 8);
    *(short8*)&Wl[n * HID + ((c ^ (n & 15)) << 3)] = w;
  }
  float bcol[8];
#pragma unroll
  for (int ct = 0; ct < 8; ++ct) bcol[ct] = b1[ct * 16 + l15];

  float pooled[8] = {0.f, 0.f, 0.f, 0.f, 0.f, 0.f, 0.f, 0.f};
  float hp[8] = {0.f, 0.f, 0.f, 0.f, 0.f, 0.f, 0.f, 0.f};

  for (int pass = 0; pass < 4; ++pass) {
    __syncthreads();
    for (int i = tid; i < 64 * 16; i += 256) {
      const int r = i >> 4;
      const int c8 = i & 15;   // == tid&15 (stride 256)
      const int rowi = pass * 64 + r;
      short8 o = {0, 0, 0, 0, 0, 0, 0, 0};
      if (rowi < NSTRIP) {
        const int node = base + rowi;
        const short8 xs = *(const short8*)(Xb + (size_t)node * HID + c8 * 8);
        const float4 Aa = *(const float4*)(An + (size_t)g * HID + c8 * 8);
        const float4 Ab = *(const float4*)(An + (size_t)g * HID + c8 * 8 + 4);
        const float4 Ba = *(const float4*)(Bn + (size_t)g * HID + c8 * 8);
        const float4 Bb = *(const float4*)(Bn + (size_t)g * HID + c8 * 8 + 4);
        const float Av[8] = {Aa.x, Aa.y, Aa.z, Aa.w, Ab.x, Ab.y, Ab.z, Ab.w};
        const float Bv[8] = {Ba.x, Ba.y, Ba.z, Ba.w, Bb.x, Bb.y, Bb.z, Bb.w};
#pragma unroll
        for (int j = 0; j < 8; ++j) {
          const float xn = leaky(fmaf(Av[j], bf2f((u16)xs[j]), Bv[j]));
          hp[j] += xn;
          o[j] = (short)f2bf(xn);
        }
      }
      *(short8*)&Xl[r * HID + ((c8 ^ (r & 15)) << 3)] = o;
    }
    __syncthreads();
    short8 a[4];
    const int arow = wave * 16 + l15;
#pragma unroll
    for (int kt = 0; kt < 4; ++kt)
      a[kt] = *(const short8*)&Xl[arow * HID + (((kt * 4 + quad) ^ l15) << 3)];
#pragma unroll
    for (int ct = 0; ct < 8; ++ct) {
      f32x4 acc = {0.f, 0.f, 0.f, 0.f};
      const int brow = ct * 16 + l15;
#pragma unroll
      for (int kt = 0; kt < 4; ++kt) {
        const short8 b = *(const short8*)&Wl[brow * HID + (((kt * 4 + quad) ^ l15) << 3)];
        acc = __builtin_amdgcn_mfma_f32_16x16x32_bf16(a[kt], b, acc, 0, 0, 0);
      }
#pragma unroll
      for (int r = 0; r < 4; ++r) {
        const int rowi = pass * 64 + wave * 16 + quad * 4 + r;
        if (rowi < NSTRIP) pooled[ct] += leaky(acc[r] + bcol[ct]);
      }
    }
  }
  const int qi = wave * 4 + quad;
#pragma unroll
  for (int ct = 0; ct < 8; ++ct) red[qi][ct * 16 + l15] = pooled[ct];
#pragma unroll
  for (int j = 0; j < 8; ++j) hred[tid >> 4][(tid & 15) * 8 + j] = hp[j];
  __syncthreads();
  if (tid < HID) {
    float s = 0.f;
#pragma unroll
    for (int q = 0; q < 16; ++q) s += red[q][tid];
    unsafeAtomicAdd(&phi_sum[g * HID + tid], s);
  } else {
    const int t = tid - HID;
    float s = 0.f;
#pragma unroll
    for (int rr = 0; rr < 16; ++rr) s += hred[rr][t];
    unsafeAtomicAdd(&h_sum[g * HID + t], s);
  }
}

// ---------------------------------------------------------------------------
// Gather: scalar-pipe CSR records + TWO independent node-chains per wave.
// Per pair: 2 s_load_dwordx4 + 8 saddr vmem in flight, then 16 FMAs —
// breaks the one-chain-per-wave latency serialization (R11 VALUBusy 28%).
// ---------------------------------------------------------------------------
__global__ __launch_bounds__(256) void gather_k(const u16* __restrict__ H,
                                                const unsigned* __restrict__ csr,
                                                const int* __restrict__ offs,
                                                const int* __restrict__ cin_,
                                                u16* __restrict__ AGG,
                                                float* __restrict__ sx,
                                                float* __restrict__ sq) {
  __shared__ float redx[4][HID];
  __shared__ float redq[4][HID];
  const int wave = threadIdx.x >> 6;
  const int lane = threadIdx.x & 63;
  int g, part;
  if (!swz(blockIdx.x, 25, g, part)) return;
  const int nb = g * NPG;
  const int base = nb + part * GSN;
  const int loff = lane * 2;
  const u16* __restrict__ Hg = H + (size_t)nb * HID;

  float sxa = 0.f, sxb = 0.f, sqa = 0.f, sqb = 0.f;
  for (int i = 0; i < 5; ++i) {               // 2 nodes per iter: nA, nA+20
    const int nA = base + wave + i * 4;
    const int nB = nA + GSN / 2;
    const int nuA = __builtin_amdgcn_readfirstlane(nA);
    const int nuB = __builtin_amdgcn_readfirstlane(nB);
    const int offA = __builtin_amdgcn_readfirstlane(offs[nuA]);
    const int cntA = __builtin_amdgcn_readfirstlane(cin_[nuA]);
    const int offB = __builtin_amdgcn_readfirstlane(offs[nuB]);
    const int cntB = __builtin_amdgcn_readfirstlane(cin_[nuB]);
    const float isqA = rsqrtf(fmaxf((float)cntA, 1.0f));
    const float isqB = rsqrtf(fmaxf((float)cntB, 1.0f));
    const uint4* __restrict__ pA =
        (const uint4*)__builtin_assume_aligned(csr + offA, 16);
    const uint4* __restrict__ pB =
        (const uint4*)__builtin_assume_aligned(csr + offB, 16);
    float axA = 0.f, ayA = 0.f, bxA = 0.f, byA = 0.f;
    float axB = 0.f, ayB = 0.f, bxB = 0.f, byB = 0.f;
    const int c4A = cntA >> 2, c4B = cntB >> 2;
    const int common = min(c4A, c4B);
    int t = 0;
    for (; t < common; ++t) {                 // interleaved: 2 chains in flight
      const uint4 rA = pA[t];
      const uint4 rB = pB[t];
      const unsigned a0 = *(const unsigned*)(Hg + (size_t)(rA.x >> 16) * HID + loff);
      const unsigned a1 = *(const unsigned*)(Hg + (size_t)(rA.y >> 16) * HID + loff);
      const unsigned a2 = *(const unsigned*)(Hg + (size_t)(rA.z >> 16) * HID + loff);
      const unsigned a3 = *(const unsigned*)(Hg + (size_t)(rA.w >> 16) * HID + loff);
      const unsigned b0 = *(const unsigned*)(Hg + (size_t)(rB.x >> 16) * HID + loff);
      const unsigned b1 = *(const unsigned*)(Hg + (size_t)(rB.y >> 16) * HID + loff);
      const unsigned b2 = *(const unsigned*)(Hg + (size_t)(rB.z >> 16) * HID + loff);
      const unsigned b3 = *(const unsigned*)(Hg + (size_t)(rB.w >> 16) * HID + loff);
      const float wA0 = bf2f((u16)(rA.x & 0xffffu));
      const float wA1 = bf2f((u16)(rA.y & 0xffffu));
      const float wA2 = bf2f((u16)(rA.z & 0xffffu));
      const float wA3 = bf2f((u16)(rA.w & 0xffffu));
      const float wB0 = bf2f((u16)(rB.x & 0xffffu));
      const float wB1 = bf2f((u16)(rB.y & 0xffffu));
      const float wB2 = bf2f((u16)(rB.z & 0xffffu));
      const float wB3 = bf2f((u16)(rB.w & 0xffffu));
      axA = fmaf(wA0, __uint_as_float(a0 << 16), axA);
      ayA = fmaf(wA0, __uint_as_float(a0 & 0xffff0000u), ayA);
      bxA = fmaf(wA1, __uint_as_float(a1 << 16), bxA);
      byA = fmaf(wA1, __uint_as_float(a1 & 0xffff0000u), byA);
      axA = fmaf(wA2, __uint_as_float(a2 << 16), axA);
      ayA = fmaf(wA2, __uint_as_float(a2 & 0xffff0000u), ayA);
      bxA = fmaf(wA3, __uint_as_float(a3 << 16), bxA);
      byA = fmaf(wA3, __uint_as_float(a3 & 0xffff0000u), byA);
      axB = fmaf(wB0, __uint_as_float(b0 << 16), axB);
      ayB = fmaf(wB0, __uint_as_float(b0 & 0xffff0000u), ayB);
      bxB = fmaf(wB1, __uint_as_float(b1 << 16), bxB);
      byB = fmaf(wB1, __uint_as_float(b1 & 0xffff0000u), byB);
      axB = fmaf(wB2, __uint_as_float(b2 << 16), axB);
      ayB = fmaf(wB2, __uint_as_float(b2 & 0xffff0000u), ayB);
      bxB = fmaf(wB3, __uint_as_float(b3 << 16), bxB);
      byB = fmaf(wB3, __uint_as_float(b3 & 0xffff0000u), byB);
    }
    for (int ta = t; ta < c4A; ++ta) {        // drain A
      const uint4 rA = pA[ta];
      const unsigned a0 = *(const unsigned*)(Hg + (size_t)(rA.x >> 16) * HID + loff);
      const unsigned a1 = *(const unsigned*)(Hg + (size_t)(rA.y >> 16) * HID + loff);
      const unsigned a2 = *(const unsigned*)(Hg + (size_t)(rA.z >> 16) * HID + loff);
      const unsigned a3 = *(const unsigned*)(Hg + (size_t)(rA.w >> 16) * HID + loff);
      const float w0 = bf2f((u16)(rA.x & 0xffffu));
      const float w1 = bf2f((u16)(rA.y & 0xffffu));
      const float w2 = bf2f((u16)(rA.z & 0xffffu));
      const float w3 = bf2f((u16)(rA.w & 0xffffu));
      axA = fmaf(w0, __uint_as_float(a0 << 16), axA);
      ayA = fmaf(w0, __uint_as_float(a0 & 0xffff0000u), ayA);
      bxA = fmaf(w1, __uint_as_float(a1 << 16), bxA);
      byA = fmaf(w1, __uint_as_float(a1 & 0xffff0000u), byA);
      axA = fmaf(w2, __uint_as_float(a2 << 16), axA);
      ayA = fmaf(w2, __uint_as_float(a2 & 0xffff0000u), ayA);
      bxA = fmaf(w3, __uint_as_float(a3 << 16), bxA);
      byA = fmaf(w3, __uint_as_float(a3 & 0xffff0000u), byA);
    }
    for (int tb = t; tb < c4B; ++tb) {        // drain B
      const uint4 rB = pB[tb];
      const unsigned b0 = *(const unsigned*)(Hg + (size_t)(rB.x >> 16) * HID + loff);
      const unsigned b1 = *(const unsigned*)(Hg + (size_t)(rB.y >> 16) * HID + loff);
      const unsigned b2 = *(const unsigned*)(Hg + (size_t)(rB.z >> 16) * HID + loff);
      const unsigned b3 = *(const unsigned*)(Hg + (size_t)(rB.w >> 16) * HID + loff);
      const float w0 = bf2f((u16)(rB.x & 0xffffu));
      const float w1 = bf2f((u16)(rB.y & 0xffffu));
      const float w2 = bf2f((u16)(rB.z & 0xffffu));
      const float w3 = bf2f((u16)(rB.w & 0xffffu));
      axB = fmaf(w0, __uint_as_float(b0 << 16), axB);
      ayB = fmaf(w0, __uint_as_float(b0 & 0xffff0000u), ayB);
      bxB = fmaf(w1, __uint_as_float(b1 << 16), bxB);
      byB = fmaf(w1, __uint_as_float(b1 & 0xffff0000u), byB);
      axB = fmaf(w2, __uint_as_float(b2 << 16), axB);
      ayB = fmaf(w2, __uint_as_float(b2 & 0xffff0000u), ayB);
      bxB = fmaf(w3, __uint_as_float(b3 << 16), bxB);
      byB = fmaf(w3, __uint_as_float(b3 & 0xffff0000u), byB);
    }
    for (int k = c4A << 2; k < cntA; ++k) {   // tail A (0-3 records)
      const unsigned r0 = csr[offA + k];
      const float w = bf2f((u16)(r0 & 0xffffu));
      const unsigned u0 = *(const unsigned*)(Hg + (size_t)(r0 >> 16) * HID + loff);
      axA = fmaf(w, __uint_as_float(u0 << 16), axA);
      ayA = fmaf(w, __uint_as_float(u0 & 0xffff0000u), ayA);
    }
    for (int k = c4B << 2; k < cntB; ++k) {   // tail B
      const unsigned r0 = csr[offB + k];
      const float w = bf2f((u16)(r0 & 0xffffu));
      const unsigned u0 = *(const unsigned*)(Hg + (size_t)(r0 >> 16) * HID + loff);
      axB = fmaf(w, __uint_as_float(u0 << 16), axB);
      ayB = fmaf(w, __uint_as_float(u0 & 0xffff0000u), ayB);
    }
    const float rxA = (axA + bxA) * isqA;
    const float ryA = (ayA + byA) * isqA;
    const float rxB = (axB + bxB) * isqB;
    const float ryB = (ayB + byB) * isqB;
    *(unsigned*)(AGG + (size_t)nA * HID + loff) =
        (unsigned)f2bf(rxA) | ((unsigned)f2bf(ryA) << 16);
    *(unsigned*)(AGG + (size_t)nB * HID + loff) =
        (unsigned)f2bf(rxB) | ((unsigned)f2bf(ryB) << 16);
    sxa += rxA + rxB; sxb += ryA + ryB;
    sqa += rxA * rxA + rxB * rxB;
    sqb += ryA * ryA + ryB * ryB;
  }
  redx[wave][loff] = sxa; redx[wave][loff + 1] = sxb;
  redq[wave][loff] = sqa; redq[wave][loff + 1] = sqb;
  __syncthreads();
  const int tid = threadIdx.x;
  if (tid < HID) {
    unsafeAtomicAdd(&sx[g * HID + tid],
                    redx[0][tid] + redx[1][tid] + redx[2][tid] + redx[3][tid]);
  } else {
    const int t = tid - HID;
    unsafeAtomicAdd(&sq[g * HID + t],
                    redq[0][t] + redq[1][t] + redq[2][t] + redq[3][t]);
  }
}

// ---------------------------------------------------------------------------
// Fold stats into affine: normalized = A*x + B per (graph, feat).
// ---------------------------------------------------------------------------
__global__ __launch_bounds__(HID) void stats_k(const float* __restrict__ sx,
                                               const float* __restrict__ sq,
                                               const float* __restrict__ alpha,
                                               const float* __restrict__ gamma,
                                               const float* __restrict__ beta,
                                               float* __restrict__ An,
                                               float* __restrict__ Bn) {
  const int g = (blockIdx.x & 7) + 8 * (blockIdx.x >> 3);
  if (g >= NG) return;
  const int j = threadIdx.x;
  const float mean = sx[g * HID + j] * (1.0f / NPG);
  const float ex2 = sq[g * HID + j] * (1.0f / NPG);
  const float am = alpha[j] * mean;
  float var = ex2 - 2.0f * am * mean + am * am;
  var = fmaxf(var, 0.0f);
  const float rstd = rsqrtf(var + EPSV);
  const float A = gamma[j] * rstd;
  An[g * HID + j] = A;
  Bn[g * HID + j] = beta[j] - A * am;
}

// ---------------------------------------------------------------------------
// Readout part 2.
// ---------------------------------------------------------------------------
__global__ __launch_bounds__(64) void finalize_k(const float* __restrict__ phi_sum,
                                                 const float* __restrict__ h_sum,
                                                 const float* __restrict__ w2,
                                                 const float* __restrict__ b2,
                                                 float* __restrict__ out,
                                                 int roff, int moff) {
  const int g = blockIdx.x;
  const int j = threadIdx.x;  // 0..63
  float acc = b2[j];
#pragma unroll 8
  for (int k = 0; k < HID; ++k)
    acc += (phi_sum[g * HID + k] * (1.0f / NPG)) * w2[k * RD + j];
  const float r = leaky(acc);
  out[g * 384 + roff + j] = leaky(r);
  out[g * 384 + moff + j] = leaky(h_sum[g * HID + j] * (1.0f / NPG));
  out[g * 384 + moff + 64 + j] = leaky(h_sum[g * HID + 64 + j] * (1.0f / NPG));
}

// ---------------------------------------------------------------------------
extern "C" void kernel_launch(void* const* d_in, const int* in_sizes, int n_in,
                              void* d_out, int out_size, void* d_ws, size_t ws_size,
                              hipStream_t stream) {
  const float* node_feats = (const float*)d_in[0];
  const float* ew   = (const float*)d_in[1];
  const float* W1   = (const float*)d_in[2];
  const float* W2   = (const float*)d_in[3];
  const float* g1a  = (const float*)d_in[4];
  const float* g1g  = (const float*)d_in[5];
  const float* g1b  = (const float*)d_in[6];
  const float* g2a  = (const float*)d_in[7];
  const float* g2g  = (const float*)d_in[8];
  const float* g2b  = (const float*)d_in[9];
  const float* r1w1 = (const float*)d_in[10];
  const float* r1b1 = (const float*)d_in[11];
  const float* r1w2 = (const float*)d_in[12];
  const float* r1b2 = (const float*)d_in[13];
  const float* r2w1 = (const float*)d_in[14];
  const float* r2b1 = (const float*)d_in[15];
  const float* r2w2 = (const float*)d_in[16];
  const float* r2b2 = (const float*)d_in[17];
  const int* src = (const int*)d_in[18];
  const int* dst = (const int*)d_in[19];
  float* out = (float*)d_out;

  // workspace layout (zeroed region first: phi/h pooled sums + sx/sq)
  char* wsb = (char*)d_ws;
  float* ps1     = (float*)wsb;                       // NG*HID x8, zeroed
  float* hs1     = ps1 + NG * HID;
  float* ps2     = hs1 + NG * HID;
  float* hs2     = ps2 + NG * HID;
  float* sx1     = hs2 + NG * HID;
  float* sq1     = sx1 + NG * HID;
  float* sx2     = sq1 + NG * HID;
  float* sq2     = sx2 + NG * HID;
  int*   cin     = (int*)(sq2 + NG * HID);            // NN (direct store)
  int*   cout_   = cin + NN;                          // NN (direct store)
  int*   offs    = cout_ + NN;                        // NN (direct store)
  unsigned* csr  = (unsigned*)(offs + NN);            // NG*CSRG packed dwords (8 MB)
  float* A1      = (float*)(csr + (size_t)NG * CSRG); // NG*HID x4
  float* B1      = A1 + NG * HID;
  float* A2      = B1 + NG * HID;
  float* B2      = A2 + NG * HID;
  u16*   Wt1     = (u16*)(B2 + NG * HID);             // 128*64
  u16*   Wt2     = Wt1 + HID * FIN;                   // 128*128 x3
  u16*   Rt1     = Wt2 + HID * HID;
  u16*   Rt2     = Rt1 + HID * HID;
  u16*   bufA    = Rt2 + HID * HID;                   // NN*HID bf16
  u16*   bufB    = bufA + (size_t)NN * HID;           // NN*HID bf16

  hipMemsetAsync(d_ws, 0, (size_t)(8 * NG * HID) * sizeof(float), stream);

  // weight transpose + per-graph CSR build (per call)
  wt_k<<<(FIN * HID + 3 * HID * HID) / 256, 256, 0, stream>>>(
      W1, W2, r1w1, r2w1, Wt1, Wt2, Rt1, Rt2);
  build_k<<<8 * 13, 1024, 0, stream>>>(src, dst, ew, cin, cout_, offs, csr);

  const int gemm_grid = 8 * 4 * 13;     // XCD-swizzled, 4 strips/graph
  const int gather_grid = 8 * 25 * 13;  // XCD-swizzled, 25 strips/graph
  const int stats_grid = 8 * 13;

  // ---- layer 1 ----
  gemm1_k<<<gemm_grid, 256, 0, stream>>>(node_feats, Wt1, cout_, bufA);
  gather_k<<<gather_grid, 256, 0, stream>>>(bufA, csr, offs, cin, bufB, sx1, sq1);
  stats_k<<<stats_grid, HID, 0, stream>>>(sx1, sq1, g1a, g1g, g1b, A1, B1);
  phi_pool_k<<<gemm_grid, 256, 0, stream>>>(bufB, A1, B1, Rt1, r1b1, ps1, hs1);
  finalize_k<<<NG, 64, 0, stream>>>(ps1, hs1, r1w2, r1b2, out, 0, 64);

  // ---- layer 2 ----
  gemm_norm_k<<<gemm_grid, 256, 0, stream>>>(bufB, Wt2, A1, B1, cout_, bufA);
  gather_k<<<gather_grid, 256, 0, stream>>>(bufA, csr, offs, cin, bufB, sx2, sq2);
  stats_k<<<stats_grid, HID, 0, stream>>>(sx2, sq2, g2a, g2g, g2b, A2, B2);
  phi_pool_k<<<gemm_grid, 256, 0, stream>>>(bufB, A2, B2, Rt2, r2b1, ps2, hs2);
  finalize_k<<<NG, 64, 0, stream>>>(ps2, hs2, r2w2, r2b2, out, 192, 256);
}

// Round 13
// 297.238 us; speedup vs baseline: 1.2282x; 1.0744x over previous
//
#include <hip/hip_runtime.h>
#include <cstddef>
#include <cstdint>

#define NG   100
#define NPG  1000
#define NN   (NG * NPG)       // 100000 nodes
#define NE   (NN * 16)        // 1600000 edges
#define EPG  (NE / NG)        // 16000 edges per graph (edges are graph-local)
#define CSRG 20000            // CSR capacity/graph (4-aligned segments)
#define FIN  64
#define HID  128
#define RD   64
#define SLOPE 0.01f
#define EPSV  1e-5f
#define NSTRIP 250            // nodes per GEMM/phi block (4 strips per graph)
#define GSN   40              // nodes per gather block (25 strips per graph)

using short8 = __attribute__((ext_vector_type(8))) short;   // 8 bf16 = 4 VGPRs
using f32x4  = __attribute__((ext_vector_type(4))) float;
typedef unsigned short u16;

__device__ __forceinline__ float leaky(float x) { return x >= 0.f ? x : SLOPE * x; }

// fp32 -> bf16 (round-to-nearest-even), bit pattern
__device__ __forceinline__ u16 f2bf(float f) {
  union { float f; unsigned u; } v; v.f = f;
  return (u16)((v.u + 0x7fffu + ((v.u >> 16) & 1u)) >> 16);
}
__device__ __forceinline__ float bf2f(u16 u) {
  union { unsigned u; float f; } v; v.u = ((unsigned)u) << 16;
  return v.f;
}

// XCD-affinity swizzle: block->XCD heuristic is blockIdx%8; pin graph g to
// XCD g%8 so producer/consumer blocks of one graph share an L2.
__device__ __forceinline__ bool swz(int b, int per_g, int& g, int& part) {
  const int xcd = b & 7;
  const int slot = b >> 3;
  g = xcd + 8 * (slot / per_g);
  part = slot % per_g;
  return g < NG;
}

// ---------------------------------------------------------------------------
// One-shot bf16 transpose of the four GEMM weight matrices: Wt[n][k]=W[k][n].
// ---------------------------------------------------------------------------
__global__ __launch_bounds__(256) void wt_k(const float* __restrict__ W1,
                                            const float* __restrict__ W2,
                                            const float* __restrict__ R1,
                                            const float* __restrict__ R2,
                                            u16* __restrict__ Wt1,
                                            u16* __restrict__ Wt2,
                                            u16* __restrict__ Rt1,
                                            u16* __restrict__ Rt2) {
  const int idx = blockIdx.x * 256 + threadIdx.x;  // 57344 total
  if (idx < FIN * HID) {
    const int n = idx >> 6, k = idx & 63;          // Wt1 [128][64]
    Wt1[idx] = f2bf(W1[k * HID + n]);
  } else {
    const int j = idx - FIN * HID;
    const int m = j >> 14, r = j & 16383;
    const int n = r >> 7, k = r & 127;
    const float* s = (m == 0) ? W2 : (m == 1) ? R1 : R2;
    u16* d = (m == 0) ? Wt2 : (m == 1) ? Rt1 : Rt2;
    d[r] = f2bf(s[k * HID + n]);
  }
}

// ---------------------------------------------------------------------------
// Per-graph CSR build, 4-edge batched loads (HBM latency hiding). CSR record
// = packed dword {src_local:16 | bf16(w):16}; node segments 16B-aligned.
// ---------------------------------------------------------------------------
__global__ __launch_bounds__(1024) void build_k(const int* __restrict__ src,
                                                const int* __restrict__ dst,
                                                const float* __restrict__ ew,
                                                int* __restrict__ cin_,
                                                int* __restrict__ cout_,
                                                int* __restrict__ offs,
                                                unsigned* __restrict__ csr) {
  __shared__ int hin[NPG];
  __shared__ int hout[NPG];
  __shared__ int cur[NPG];
  __shared__ int wtot[16];
  int g, part;
  if (!swz(blockIdx.x, 1, g, part)) return;   // grid 8*13 = 104, 4 idle
  const int t = threadIdx.x;
  const int lane = t & 63, wave = t >> 6;
  const int nb = g * NPG, eb = g * EPG;
  if (t < NPG) { hin[t] = 0; hout[t] = 0; }
  __syncthreads();
  // pass 1: histograms, 4 edges in flight per thread
  for (int e = t; e < EPG; e += 4096) {
    int s4[4], d4[4];
#pragma unroll
    for (int k = 0; k < 4; ++k) {
      const int ee = e + k * 1024;
      if (ee < EPG) { s4[k] = src[eb + ee]; d4[k] = dst[eb + ee]; }
      else d4[k] = -1;
    }
#pragma unroll
    for (int k = 0; k < 4; ++k)
      if (d4[k] >= 0) {
        atomicAdd(&hout[s4[k] - nb], 1);
        atomicAdd(&hin[d4[k] - nb], 1);
      }
  }
  __syncthreads();
  int v[4], vr[4];
  int loc = 0;
#pragma unroll
  for (int k = 0; k < 4; ++k) {
    const int idx = t * 4 + k;
    v[k] = (idx < NPG) ? hin[idx] : 0;
    vr[k] = (v[k] + 3) & ~3;          // 4-record-aligned segment size
    loc += vr[k];
  }
  // intra-wave inclusive scan of loc (6 shuffle steps, no barriers)
  int incl = loc;
#pragma unroll
  for (int d = 1; d < 64; d <<= 1) {
    const int x = __shfl_up(incl, d);
    if (lane >= d) incl += x;
  }
  if (lane == 63) wtot[wave] = incl;
  if (t < NPG) { cin_[nb + t] = hin[t]; cout_[nb + t] = hout[t]; }
  __syncthreads();
  int wexc = 0;
  for (int i = 0; i < wave; ++i) wexc += wtot[i];   // broadcast LDS reads
  int run = g * CSRG + wexc + (incl - loc);         // exclusive prefix, aligned
#pragma unroll
  for (int k = 0; k < 4; ++k) {
    const int idx = t * 4 + k;
    if (idx < NPG) {
      offs[nb + idx] = run;
      cur[idx] = run;
      run += vr[k];
    }
  }
  __syncthreads();
  // pass 2: slot records, 4 edges in flight
  for (int e = t; e < EPG; e += 4096) {
    int s4[4], d4[4]; float w4[4];
#pragma unroll
    for (int k = 0; k < 4; ++k) {
      const int ee = e + k * 1024;
      if (ee < EPG) { s4[k] = src[eb + ee]; d4[k] = dst[eb + ee]; w4[k] = ew[eb + ee]; }
      else d4[k] = -1;
    }
#pragma unroll
    for (int k = 0; k < 4; ++k)
      if (d4[k] >= 0) {
        const int pos = atomicAdd(&cur[d4[k] - nb], 1);
        csr[pos] = ((unsigned)(s4[k] - nb) << 16) | (unsigned)f2bf(w4[k]);
      }
  }
}

// ---------------------------------------------------------------------------
// Layer-1 GEMM (MFMA bf16), XCD-swizzled, register X-prefetch, bf16 output.
// ---------------------------------------------------------------------------
__global__ __launch_bounds__(256) void gemm1_k(const float* __restrict__ X,
                                               const u16* __restrict__ Wt,
                                               const int* __restrict__ cout_,
                                               u16* __restrict__ Y) {
  __shared__ u16 Xl[64 * FIN];
  __shared__ u16 Wl[HID * FIN];
  const int tid = threadIdx.x;
  const int wave = tid >> 6, lane = tid & 63, l15 = lane & 15, quad = lane >> 4;
  int g, part;
  if (!swz(blockIdx.x, 4, g, part)) return;
  const int base = g * NPG + part * NSTRIP;
  const int kq = tid & 15;     // fixed col chunk
  const int srow = tid >> 4;   // staging row base

  for (int i = tid; i < HID * (FIN / 8); i += 256) {  // 1024 chunks
    const int n = i >> 3, c = i & 7;
    const short8 w = *(const short8*)(Wt + n * FIN + c * 8);
    *(short8*)&Wl[n * FIN + ((c ^ (n & 7)) << 3)] = w;
  }
  float4 xpre[4];
#pragma unroll
  for (int it = 0; it < 4; ++it) {
    const int rowi = srow + it * 16;
    xpre[it] = (rowi < NSTRIP) ? *(const float4*)(X + (size_t)(base + rowi) * FIN + kq * 4)
                               : make_float4(0.f, 0.f, 0.f, 0.f);
  }
  for (int pass = 0; pass < 4; ++pass) {
    __syncthreads();
#pragma unroll
    for (int it = 0; it < 4; ++it) {
      const int r = srow + it * 16;
      ushort4 u = make_ushort4(f2bf(xpre[it].x), f2bf(xpre[it].y),
                               f2bf(xpre[it].z), f2bf(xpre[it].w));
      const int c = kq >> 1, half = kq & 1;
      *(ushort4*)&Xl[r * FIN + (((c ^ (r & 7)) << 3) | (half << 2))] = u;
    }
    __syncthreads();
    if (pass < 3) {
#pragma unroll
      for (int it = 0; it < 4; ++it) {
        const int rowi = (pass + 1) * 64 + srow + it * 16;
        xpre[it] = (rowi < NSTRIP) ? *(const float4*)(X + (size_t)(base + rowi) * FIN + kq * 4)
                                   : make_float4(0.f, 0.f, 0.f, 0.f);
      }
    }
    short8 a[2];
    const int arow = wave * 16 + l15;
#pragma unroll
    for (int kt = 0; kt < 2; ++kt)
      a[kt] = *(const short8*)&Xl[arow * FIN + (((kt * 4 + quad) ^ (l15 & 7)) << 3)];
    float sc[4];
    int rows[4];
#pragma unroll
    for (int r = 0; r < 4; ++r) {
      rows[r] = pass * 64 + wave * 16 + quad * 4 + r;
      sc[r] = (rows[r] < NSTRIP) ? rsqrtf(fmaxf((float)cout_[base + rows[r]], 1.0f)) : 0.f;
    }
#pragma unroll
    for (int ct = 0; ct < 8; ++ct) {
      f32x4 acc = {0.f, 0.f, 0.f, 0.f};
      const int brow = ct * 16 + l15;
#pragma unroll
      for (int kt = 0; kt < 2; ++kt) {
        const short8 b = *(const short8*)&Wl[brow * FIN + (((kt * 4 + quad) ^ (l15 & 7)) << 3)];
        acc = __builtin_amdgcn_mfma_f32_16x16x32_bf16(a[kt], b, acc, 0, 0, 0);
      }
      const int n = ct * 16 + l15;
#pragma unroll
      for (int r = 0; r < 4; ++r)
        if (rows[r] < NSTRIP) Y[(size_t)(base + rows[r]) * HID + n] = f2bf(acc[r] * sc[r]);
    }
  }
}

// ---------------------------------------------------------------------------
// Layer-2 GEMM (MFMA bf16), fused norm apply, hoisted affine + X prefetch.
// ---------------------------------------------------------------------------
__global__ __launch_bounds__(256) void gemm_norm_k(const u16* __restrict__ Xb,
                                                   const u16* __restrict__ Wt,
                                                   const float* __restrict__ An,
                                                   const float* __restrict__ Bn,
                                                   const int* __restrict__ cout_,
                                                   u16* __restrict__ Y) {
  __shared__ u16 Xl[64 * HID];
  __shared__ u16 Wl[HID * HID];
  const int tid = threadIdx.x;
  const int wave = tid >> 6, lane = tid & 63, l15 = lane & 15, quad = lane >> 4;
  int g, part;
  if (!swz(blockIdx.x, 4, g, part)) return;
  const int base = g * NPG + part * NSTRIP;
  const int c8 = tid & 15;
  const int srow = tid >> 4;

  for (int i = tid; i < HID * (HID / 8); i += 256) {  // 2048 chunks
    const int n = i >> 4, c = i & 15;
    const short8 w = *(const short8*)(Wt + n * HID + c * 8);
    *(short8*)&Wl[n * HID + ((c ^ (n & 15)) << 3)] = w;
  }
  float Av[8], Bv[8];
  {
    const float4 Aa = *(const float4*)(An + (size_t)g * HID + c8 * 8);
    const float4 Ab = *(const float4*)(An + (size_t)g * HID + c8 * 8 + 4);
    const float4 Ba = *(const float4*)(Bn + (size_t)g * HID + c8 * 8);
    const float4 Bb = *(const float4*)(Bn + (size_t)g * HID + c8 * 8 + 4);
    Av[0] = Aa.x; Av[1] = Aa.y; Av[2] = Aa.z; Av[3] = Aa.w;
    Av[4] = Ab.x; Av[5] = Ab.y; Av[6] = Ab.z; Av[7] = Ab.w;
    Bv[0] = Ba.x; Bv[1] = Ba.y; Bv[2] = Ba.z; Bv[3] = Ba.w;
    Bv[4] = Bb.x; Bv[5] = Bb.y; Bv[6] = Bb.z; Bv[7] = Bb.w;
  }
  const short8 z8 = {0, 0, 0, 0, 0, 0, 0, 0};
  short8 xpre[4];
#pragma unroll
  for (int it = 0; it < 4; ++it) {
    const int rowi = srow + it * 16;
    xpre[it] = (rowi < NSTRIP) ? *(const short8*)(Xb + (size_t)(base + rowi) * HID + c8 * 8) : z8;
  }
  for (int pass = 0; pass < 4; ++pass) {
    __syncthreads();
#pragma unroll
    for (int it = 0; it < 4; ++it) {
      const int r = srow + it * 16;
      const int rowi = pass * 64 + r;
      short8 o = z8;
      if (rowi < NSTRIP) {
#pragma unroll
        for (int j = 0; j < 8; ++j)
          o[j] = (short)f2bf(leaky(fmaf(Av[j], bf2f((u16)xpre[it][j]), Bv[j])));
      }
      *(short8*)&Xl[r * HID + ((c8 ^ (r & 15)) << 3)] = o;
    }
    __syncthreads();
    if (pass < 3) {
#pragma unroll
      for (int it = 0; it < 4; ++it) {
        const int rowi = (pass + 1) * 64 + srow + it * 16;
        xpre[it] = (rowi < NSTRIP) ? *(const short8*)(Xb + (size_t)(base + rowi) * HID + c8 * 8) : z8;
      }
    }
    short8 a[4];
    const int arow = wave * 16 + l15;
#pragma unroll
    for (int kt = 0; kt < 4; ++kt)
      a[kt] = *(const short8*)&Xl[arow * HID + (((kt * 4 + quad) ^ l15) << 3)];
    float sc[4];
    int rows[4];
#pragma unroll
    for (int r = 0; r < 4; ++r) {
      rows[r] = pass * 64 + wave * 16 + quad * 4 + r;
      sc[r] = (rows[r] < NSTRIP) ? rsqrtf(fmaxf((float)cout_[base + rows[r]], 1.0f)) : 0.f;
    }
#pragma unroll
    for (int ct = 0; ct < 8; ++ct) {
      f32x4 acc = {0.f, 0.f, 0.f, 0.f};
      const int brow = ct * 16 + l15;
#pragma unroll
      for (int kt = 0; kt < 4; ++kt) {
        const short8 b = *(const short8*)&Wl[brow * HID + (((kt * 4 + quad) ^ l15) << 3)];
        acc = __builtin_amdgcn_mfma_f32_16x16x32_bf16(a[kt], b, acc, 0, 0, 0);
      }
      const int n = ct * 16 + l15;
#pragma unroll
      for (int r = 0; r < 4; ++r)
        if (rows[r] < NSTRIP) Y[(size_t)(base + rows[r]) * HID + n] = f2bf(acc[r] * sc[r]);
    }
  }
}

// ---------------------------------------------------------------------------
// Readout phi+pool (MFMA bf16): 48 KB LDS (red/hred union'd over Xl ->
// 3 blocks/CU), hoisted affine, register X prefetch.
// ---------------------------------------------------------------------------
struct RedT { float red[16][HID]; float hred[16][HID]; };  // 16 KB
union ShT { u16 Xl[64 * HID]; RedT r; };                   // 16 KB

__global__ __launch_bounds__(256) void phi_pool_k(const u16* __restrict__ Xb,
                                                  const float* __restrict__ An,
                                                  const float* __restrict__ Bn,
                                                  const u16* __restrict__ Wt,
                                                  const float* __restrict__ b1,
                                                  float* __restrict__ phi_sum,
                                                  float* __restrict__ h_sum) {
  __shared__ ShT sh;                    // 16 KB (Xl, then red/hred)
  __shared__ u16 Wl[HID * HID];         // 32 KB  -> 48 KB total
  const int tid = threadIdx.x;
  const int wave = tid >> 6, lane = tid & 63, l15 = lane & 15, quad = lane >> 4;
  int g, part;
  if (!swz(blockIdx.x, 4, g, part)) return;
  const int base = g * NPG + part * NSTRIP;
  const int c8 = tid & 15;
  const int srow = tid >> 4;

  for (int i = tid; i < HID * (HID / 8); i += 256) {
    const int n = i >> 4, c = i & 15;
    const short8 w = *(const short8*)(Wt + n * HID + c * 8);
    *(short8*)&Wl[n * HID + ((c ^ (n & 15)) << 3)] = w;
  }
  float Av[8], Bv[8];
  {
    const float4 Aa = *(const float4*)(An + (size_t)g * HID + c8 * 8);
    const float4 Ab = *(const float4*)(An + (size_t)g * HID + c8 * 8 + 4);
    const float4 Ba = *(const float4*)(Bn + (size_t)g * HID + c8 * 8);
    const float4 Bb = *(const float4*)(Bn + (size_t)g * HID + c8 * 8 + 4);
    Av[0] = Aa.x; Av[1] = Aa.y; Av[2] = Aa.z; Av[3] = Aa.w;
    Av[4] = Ab.x; Av[5] = Ab.y; Av[6] = Ab.z; Av[7] = Ab.w;
    Bv[0] = Ba.x; Bv[1] = Ba.y; Bv[2] = Ba.z; Bv[3] = Ba.w;
    Bv[4] = Bb.x; Bv[5] = Bb.y; Bv[6] = Bb.z; Bv[7] = Bb.w;
  }
  float bcol[8];
#pragma unroll
  for (int ct = 0; ct < 8; ++ct) bcol[ct] = b1[ct * 16 + l15];

  float pooled[8] = {0.f, 0.f, 0.f, 0.f, 0.f, 0.f, 0.f, 0.f};
  float hp[8] = {0.f, 0.f, 0.f, 0.f, 0.f, 0.f, 0.f, 0.f};
  const short8 z8 = {0, 0, 0, 0, 0, 0, 0, 0};
  short8 xpre[4];
#pragma unroll
  for (int it = 0; it < 4; ++it) {
    const int rowi = srow + it * 16;
    xpre[it] = (rowi < NSTRIP) ? *(const short8*)(Xb + (size_t)(base + rowi) * HID + c8 * 8) : z8;
  }
  for (int pass = 0; pass < 4; ++pass) {
    __syncthreads();
#pragma unroll
    for (int it = 0; it < 4; ++it) {
      const int r = srow + it * 16;
      const int rowi = pass * 64 + r;
      short8 o = z8;
      if (rowi < NSTRIP) {
#pragma unroll
        for (int j = 0; j < 8; ++j) {
          const float xn = leaky(fmaf(Av[j], bf2f((u16)xpre[it][j]), Bv[j]));
          hp[j] += xn;
          o[j] = (short)f2bf(xn);
        }
      }
      *(short8*)&sh.Xl[r * HID + ((c8 ^ (r & 15)) << 3)] = o;
    }
    __syncthreads();
    if (pass < 3) {
#pragma unroll
      for (int it = 0; it < 4; ++it) {
        const int rowi = (pass + 1) * 64 + srow + it * 16;
        xpre[it] = (rowi < NSTRIP) ? *(const short8*)(Xb + (size_t)(base + rowi) * HID + c8 * 8) : z8;
      }
    }
    short8 a[4];
    const int arow = wave * 16 + l15;
#pragma unroll
    for (int kt = 0; kt < 4; ++kt)
      a[kt] = *(const short8*)&sh.Xl[arow * HID + (((kt * 4 + quad) ^ l15) << 3)];
#pragma unroll
    for (int ct = 0; ct < 8; ++ct) {
      f32x4 acc = {0.f, 0.f, 0.f, 0.f};
      const int brow = ct * 16 + l15;
#pragma unroll
      for (int kt = 0; kt < 4; ++kt) {
        const short8 b = *(const short8*)&Wl[brow * HID + (((kt * 4 + quad) ^ l15) << 3)];
        acc = __builtin_amdgcn_mfma_f32_16x16x32_bf16(a[kt], b, acc, 0, 0, 0);
      }
#pragma unroll
      for (int r = 0; r < 4; ++r) {
        const int rowi = pass * 64 + wave * 16 + quad * 4 + r;
        if (rowi < NSTRIP) pooled[ct] += leaky(acc[r] + bcol[ct]);
      }
    }
  }
  __syncthreads();   // all Xl reads done -> safe to overwrite with red/hred
  const int qi = wave * 4 + quad;
#pragma unroll
  for (int ct = 0; ct < 8; ++ct) sh.r.red[qi][ct * 16 + l15] = pooled[ct];
#pragma unroll
  for (int j = 0; j < 8; ++j) sh.r.hred[tid >> 4][(tid & 15) * 8 + j] = hp[j];
  __syncthreads();
  if (tid < HID) {
    float s = 0.f;
#pragma unroll
    for (int q = 0; q < 16; ++q) s += sh.r.red[q][tid];
    unsafeAtomicAdd(&phi_sum[g * HID + tid], s);
  } else {
    const int t = tid - HID;
    float s = 0.f;
#pragma unroll
    for (int rr = 0; rr < 16; ++rr) s += sh.r.hred[rr][t];
    unsafeAtomicAdd(&h_sum[g * HID + t], s);
  }
}

// ---------------------------------------------------------------------------
// Gather: scalar-pipe CSR records + TWO independent node-chains per wave.
// ---------------------------------------------------------------------------
__global__ __launch_bounds__(256) void gather_k(const u16* __restrict__ H,
                                                const unsigned* __restrict__ csr,
                                                const int* __restrict__ offs,
                                                const int* __restrict__ cin_,
                                                u16* __restrict__ AGG,
                                                float* __restrict__ sx,
                                                float* __restrict__ sq) {
  __shared__ float redx[4][HID];
  __shared__ float redq[4][HID];
  const int wave = threadIdx.x >> 6;
  const int lane = threadIdx.x & 63;
  int g, part;
  if (!swz(blockIdx.x, 25, g, part)) return;
  const int nb = g * NPG;
  const int base = nb + part * GSN;
  const int loff = lane * 2;
  const u16* __restrict__ Hg = H + (size_t)nb * HID;

  float sxa = 0.f, sxb = 0.f, sqa = 0.f, sqb = 0.f;
  for (int i = 0; i < 5; ++i) {               // 2 nodes per iter: nA, nA+20
    const int nA = base + wave + i * 4;
    const int nB = nA + GSN / 2;
    const int nuA = __builtin_amdgcn_readfirstlane(nA);
    const int nuB = __builtin_amdgcn_readfirstlane(nB);
    const int offA = __builtin_amdgcn_readfirstlane(offs[nuA]);
    const int cntA = __builtin_amdgcn_readfirstlane(cin_[nuA]);
    const int offB = __builtin_amdgcn_readfirstlane(offs[nuB]);
    const int cntB = __builtin_amdgcn_readfirstlane(cin_[nuB]);
    const float isqA = rsqrtf(fmaxf((float)cntA, 1.0f));
    const float isqB = rsqrtf(fmaxf((float)cntB, 1.0f));
    const uint4* __restrict__ pA =
        (const uint4*)__builtin_assume_aligned(csr + offA, 16);
    const uint4* __restrict__ pB =
        (const uint4*)__builtin_assume_aligned(csr + offB, 16);
    float axA = 0.f, ayA = 0.f, bxA = 0.f, byA = 0.f;
    float axB = 0.f, ayB = 0.f, bxB = 0.f, byB = 0.f;
    const int c4A = cntA >> 2, c4B = cntB >> 2;
    const int common = min(c4A, c4B);
    int t = 0;
    for (; t < common; ++t) {                 // interleaved: 2 chains in flight
      const uint4 rA = pA[t];
      const uint4 rB = pB[t];
      const unsigned a0 = *(const unsigned*)(Hg + (size_t)(rA.x >> 16) * HID + loff);
      const unsigned a1 = *(const unsigned*)(Hg + (size_t)(rA.y >> 16) * HID + loff);
      const unsigned a2 = *(const unsigned*)(Hg + (size_t)(rA.z >> 16) * HID + loff);
      const unsigned a3 = *(const unsigned*)(Hg + (size_t)(rA.w >> 16) * HID + loff);
      const unsigned b0 = *(const unsigned*)(Hg + (size_t)(rB.x >> 16) * HID + loff);
      const unsigned b1 = *(const unsigned*)(Hg + (size_t)(rB.y >> 16) * HID + loff);
      const unsigned b2 = *(const unsigned*)(Hg + (size_t)(rB.z >> 16) * HID + loff);
      const unsigned b3 = *(const unsigned*)(Hg + (size_t)(rB.w >> 16) * HID + loff);
      const float wA0 = bf2f((u16)(rA.x & 0xffffu));
      const float wA1 = bf2f((u16)(rA.y & 0xffffu));
      const float wA2 = bf2f((u16)(rA.z & 0xffffu));
      const float wA3 = bf2f((u16)(rA.w & 0xffffu));
      const float wB0 = bf2f((u16)(rB.x & 0xffffu));
      const float wB1 = bf2f((u16)(rB.y & 0xffffu));
      const float wB2 = bf2f((u16)(rB.z & 0xffffu));
      const float wB3 = bf2f((u16)(rB.w & 0xffffu));
      axA = fmaf(wA0, __uint_as_float(a0 << 16), axA);
      ayA = fmaf(wA0, __uint_as_float(a0 & 0xffff0000u), ayA);
      bxA = fmaf(wA1, __uint_as_float(a1 << 16), bxA);
      byA = fmaf(wA1, __uint_as_float(a1 & 0xffff0000u), byA);
      axA = fmaf(wA2, __uint_as_float(a2 << 16), axA);
      ayA = fmaf(wA2, __uint_as_float(a2 & 0xffff0000u), ayA);
      bxA = fmaf(wA3, __uint_as_float(a3 << 16), bxA);
      byA = fmaf(wA3, __uint_as_float(a3 & 0xffff0000u), byA);
      axB = fmaf(wB0, __uint_as_float(b0 << 16), axB);
      ayB = fmaf(wB0, __uint_as_float(b0 & 0xffff0000u), ayB);
      bxB = fmaf(wB1, __uint_as_float(b1 << 16), bxB);
      byB = fmaf(wB1, __uint_as_float(b1 & 0xffff0000u), byB);
      axB = fmaf(wB2, __uint_as_float(b2 << 16), axB);
      ayB = fmaf(wB2, __uint_as_float(b2 & 0xffff0000u), ayB);
      bxB = fmaf(wB3, __uint_as_float(b3 << 16), bxB);
      byB = fmaf(wB3, __uint_as_float(b3 & 0xffff0000u), byB);
    }
    for (int ta = t; ta < c4A; ++ta) {        // drain A
      const uint4 rA = pA[ta];
      const unsigned a0 = *(const unsigned*)(Hg + (size_t)(rA.x >> 16) * HID + loff);
      const unsigned a1 = *(const unsigned*)(Hg + (size_t)(rA.y >> 16) * HID + loff);
      const unsigned a2 = *(const unsigned*)(Hg + (size_t)(rA.z >> 16) * HID + loff);
      const unsigned a3 = *(const unsigned*)(Hg + (size_t)(rA.w >> 16) * HID + loff);
      const float w0 = bf2f((u16)(rA.x & 0xffffu));
      const float w1 = bf2f((u16)(rA.y & 0xffffu));
      const float w2 = bf2f((u16)(rA.z & 0xffffu));
      const float w3 = bf2f((u16)(rA.w & 0xffffu));
      axA = fmaf(w0, __uint_as_float(a0 << 16), axA);
      ayA = fmaf(w0, __uint_as_float(a0 & 0xffff0000u), ayA);
      bxA = fmaf(w1, __uint_as_float(a1 << 16), bxA);
      byA = fmaf(w1, __uint_as_float(a1 & 0xffff0000u), byA);
      axA = fmaf(w2, __uint_as_float(a2 << 16), axA);
      ayA = fmaf(w2, __uint_as_float(a2 & 0xffff0000u), ayA);
      bxA = fmaf(w3, __uint_as_float(a3 << 16), bxA);
      byA = fmaf(w3, __uint_as_float(a3 & 0xffff0000u), byA);
    }
    for (int tb = t; tb < c4B; ++tb) {        // drain B
      const uint4 rB = pB[tb];
      const unsigned b0 = *(const unsigned*)(Hg + (size_t)(rB.x >> 16) * HID + loff);
      const unsigned b1 = *(const unsigned*)(Hg + (size_t)(rB.y >> 16) * HID + loff);
      const unsigned b2 = *(const unsigned*)(Hg + (size_t)(rB.z >> 16) * HID + loff);
      const unsigned b3 = *(const unsigned*)(Hg + (size_t)(rB.w >> 16) * HID + loff);
      const float w0 = bf2f((u16)(rB.x & 0xffffu));
      const float w1 = bf2f((u16)(rB.y & 0xffffu));
      const float w2 = bf2f((u16)(rB.z & 0xffffu));
      const float w3 = bf2f((u16)(rB.w & 0xffffu));
      axB = fmaf(w0, __uint_as_float(b0 << 16), axB);
      ayB = fmaf(w0, __uint_as_float(b0 & 0xffff0000u), ayB);
      bxB = fmaf(w1, __uint_as_float(b1 << 16), bxB);
      byB = fmaf(w1, __uint_as_float(b1 & 0xffff0000u), byB);
      axB = fmaf(w2, __uint_as_float(b2 << 16), axB);
      ayB = fmaf(w2, __uint_as_float(b2 & 0xffff0000u), ayB);
      bxB = fmaf(w3, __uint_as_float(b3 << 16), bxB);
      byB = fmaf(w3, __uint_as_float(b3 & 0xffff0000u), byB);
    }
    for (int k = c4A << 2; k < cntA; ++k) {   // tail A (0-3 records)
      const unsigned r0 = csr[offA + k];
      const float w = bf2f((u16)(r0 & 0xffffu));
      const unsigned u0 = *(const unsigned*)(Hg + (size_t)(r0 >> 16) * HID + loff);
      axA = fmaf(w, __uint_as_float(u0 << 16), axA);
      ayA = fmaf(w, __uint_as_float(u0 & 0xffff0000u), ayA);
    }
    for (int k = c4B << 2; k < cntB; ++k) {   // tail B
      const unsigned r0 = csr[offB + k];
      const float w = bf2f((u16)(r0 & 0xffffu));
      const unsigned u0 = *(const unsigned*)(Hg + (size_t)(r0 >> 16) * HID + loff);
      axB = fmaf(w, __uint_as_float(u0 << 16), axB);
      ayB = fmaf(w, __uint_as_float(u0 & 0xffff0000u), ayB);
    }
    const float rxA = (axA + bxA) * isqA;
    const float ryA = (ayA + byA) * isqA;
    const float rxB = (axB + bxB) * isqB;
    const float ryB = (ayB + byB) * isqB;
    *(unsigned*)(AGG + (size_t)nA * HID + loff) =
        (unsigned)f2bf(rxA) | ((unsigned)f2bf(ryA) << 16);
    *(unsigned*)(AGG + (size_t)nB * HID + loff) =
        (unsigned)f2bf(rxB) | ((unsigned)f2bf(ryB) << 16);
    sxa += rxA + rxB; sxb += ryA + ryB;
    sqa += rxA * rxA + rxB * rxB;
    sqb += ryA * ryA + ryB * ryB;
  }
  redx[wave][loff] = sxa; redx[wave][loff + 1] = sxb;
  redq[wave][loff] = sqa; redq[wave][loff + 1] = sqb;
  __syncthreads();
  const int tid = threadIdx.x;
  if (tid < HID) {
    unsafeAtomicAdd(&sx[g * HID + tid],
                    redx[0][tid] + redx[1][tid] + redx[2][tid] + redx[3][tid]);
  } else {
    const int t = tid - HID;
    unsafeAtomicAdd(&sq[g * HID + t],
                    redq[0][t] + redq[1][t] + redq[2][t] + redq[3][t]);
  }
}

// ---------------------------------------------------------------------------
// Fold stats into affine: normalized = A*x + B per (graph, feat).
// ---------------------------------------------------------------------------
__global__ __launch_bounds__(HID) void stats_k(const float* __restrict__ sx,
                                               const float* __restrict__ sq,
                                               const float* __restrict__ alpha,
                                               const float* __restrict__ gamma,
                                               const float* __restrict__ beta,
                                               float* __restrict__ An,
                                               float* __restrict__ Bn) {
  const int g = (blockIdx.x & 7) + 8 * (blockIdx.x >> 3);
  if (g >= NG) return;
  const int j = threadIdx.x;
  const float mean = sx[g * HID + j] * (1.0f / NPG);
  const float ex2 = sq[g * HID + j] * (1.0f / NPG);
  const float am = alpha[j] * mean;
  float var = ex2 - 2.0f * am * mean + am * am;
  var = fmaxf(var, 0.0f);
  const float rstd = rsqrtf(var + EPSV);
  const float A = gamma[j] * rstd;
  An[g * HID + j] = A;
  Bn[g * HID + j] = beta[j] - A * am;
}

// ---------------------------------------------------------------------------
// Readout part 2.
// ---------------------------------------------------------------------------
__global__ __launch_bounds__(64) void finalize_k(const float* __restrict__ phi_sum,
                                                 const float* __restrict__ h_sum,
                                                 const float* __restrict__ w2,
                                                 const float* __restrict__ b2,
                                                 float* __restrict__ out,
                                                 int roff, int moff) {
  const int g = blockIdx.x;
  const int j = threadIdx.x;  // 0..63
  float acc = b2[j];
#pragma unroll 8
  for (int k = 0; k < HID; ++k)
    acc += (phi_sum[g * HID + k] * (1.0f / NPG)) * w2[k * RD + j];
  const float r = leaky(acc);
  out[g * 384 + roff + j] = leaky(r);
  out[g * 384 + moff + j] = leaky(h_sum[g * HID + j] * (1.0f / NPG));
  out[g * 384 + moff + 64 + j] = leaky(h_sum[g * HID + 64 + j] * (1.0f / NPG));
}

// ---------------------------------------------------------------------------
extern "C" void kernel_launch(void* const* d_in, const int* in_sizes, int n_in,
                              void* d_out, int out_size, void* d_ws, size_t ws_size,
                              hipStream_t stream) {
  const float* node_feats = (const float*)d_in[0];
  const float* ew   = (const float*)d_in[1];
  const float* W1   = (const float*)d_in[2];
  const float* W2   = (const float*)d_in[3];
  const float* g1a  = (const float*)d_in[4];
  const float* g1g  = (const float*)d_in[5];
  const float* g1b  = (const float*)d_in[6];
  const float* g2a  = (const float*)d_in[7];
  const float* g2g  = (const float*)d_in[8];
  const float* g2b  = (const float*)d_in[9];
  const float* r1w1 = (const float*)d_in[10];
  const float* r1b1 = (const float*)d_in[11];
  const float* r1w2 = (const float*)d_in[12];
  const float* r1b2 = (const float*)d_in[13];
  const float* r2w1 = (const float*)d_in[14];
  const float* r2b1 = (const float*)d_in[15];
  const float* r2w2 = (const float*)d_in[16];
  const float* r2b2 = (const float*)d_in[17];
  const int* src = (const int*)d_in[18];
  const int* dst = (const int*)d_in[19];
  float* out = (float*)d_out;

  // workspace layout (zeroed region first: phi/h pooled sums + sx/sq)
  char* wsb = (char*)d_ws;
  float* ps1     = (float*)wsb;                       // NG*HID x8, zeroed
  float* hs1     = ps1 + NG * HID;
  float* ps2     = hs1 + NG * HID;
  float* hs2     = ps2 + NG * HID;
  float* sx1     = hs2 + NG * HID;
  float* sq1     = sx1 + NG * HID;
  float* sx2     = sq1 + NG * HID;
  float* sq2     = sx2 + NG * HID;
  int*   cin     = (int*)(sq2 + NG * HID);            // NN (direct store)
  int*   cout_   = cin + NN;                          // NN (direct store)
  int*   offs    = cout_ + NN;                        // NN (direct store)
  unsigned* csr  = (unsigned*)(offs + NN);            // NG*CSRG packed dwords (8 MB)
  float* A1      = (float*)(csr + (size_t)NG * CSRG); // NG*HID x4
  float* B1      = A1 + NG * HID;
  float* A2      = B1 + NG * HID;
  float* B2      = A2 + NG * HID;
  u16*   Wt1     = (u16*)(B2 + NG * HID);             // 128*64
  u16*   Wt2     = Wt1 + HID * FIN;                   // 128*128 x3
  u16*   Rt1     = Wt2 + HID * HID;
  u16*   Rt2     = Rt1 + HID * HID;
  u16*   bufA    = Rt2 + HID * HID;                   // NN*HID bf16
  u16*   bufB    = bufA + (size_t)NN * HID;           // NN*HID bf16

  hipMemsetAsync(d_ws, 0, (size_t)(8 * NG * HID) * sizeof(float), stream);

  // weight transpose + per-graph CSR build (per call)
  wt_k<<<(FIN * HID + 3 * HID * HID) / 256, 256, 0, stream>>>(
      W1, W2, r1w1, r2w1, Wt1, Wt2, Rt1, Rt2);
  build_k<<<8 * 13, 1024, 0, stream>>>(src, dst, ew, cin, cout_, offs, csr);

  const int gemm_grid = 8 * 4 * 13;     // XCD-swizzled, 4 strips/graph
  const int gather_grid = 8 * 25 * 13;  // XCD-swizzled, 25 strips/graph
  const int stats_grid = 8 * 13;

  // ---- layer 1 ----
  gemm1_k<<<gemm_grid, 256, 0, stream>>>(node_feats, Wt1, cout_, bufA);
  gather_k<<<gather_grid, 256, 0, stream>>>(bufA, csr, offs, cin, bufB, sx1, sq1);
  stats_k<<<stats_grid, HID, 0, stream>>>(sx1, sq1, g1a, g1g, g1b, A1, B1);
  phi_pool_k<<<gemm_grid, 256, 0, stream>>>(bufB, A1, B1, Rt1, r1b1, ps1, hs1);
  finalize_k<<<NG, 64, 0, stream>>>(ps1, hs1, r1w2, r1b2, out, 0, 64);

  // ---- layer 2 ----
  gemm_norm_k<<<gemm_grid, 256, 0, stream>>>(bufB, Wt2, A1, B1, cout_, bufA);
  gather_k<<<gather_grid, 256, 0, stream>>>(bufA, csr, offs, cin, bufB, sx2, sq2);
  stats_k<<<stats_grid, HID, 0, stream>>>(sx2, sq2, g2a, g2g, g2b, A2, B2);
  phi_pool_k<<<gemm_grid, 256, 0, stream>>>(bufB, A2, B2, Rt2, r2b1, ps2, hs2);
  finalize_k<<<NG, 64, 0, stream>>>(ps2, hs2, r2w2, r2b2, out, 192, 256);
}

// Round 14
// 294.979 us; speedup vs baseline: 1.2376x; 1.0077x over previous
//
#include <hip/hip_runtime.h>
#include <cstddef>
#include <cstdint>

#define NG   100
#define NPG  1000
#define NN   (NG * NPG)       // 100000 nodes
#define NE   (NN * 16)        // 1600000 edges
#define EPG  (NE / NG)        // 16000 edges per graph (edges are graph-local)
#define CSRG 20000            // CSR capacity/graph (4-aligned segments)
#define FIN  64
#define HID  128
#define RD   64
#define SLOPE 0.01f
#define EPSV  1e-5f
#define NSTRIP 250            // nodes per GEMM/phi block (4 strips per graph)
#define GSN   40              // nodes per gather block (25 strips per graph)

using short8 = __attribute__((ext_vector_type(8))) short;   // 8 bf16 = 4 VGPRs
using f32x4  = __attribute__((ext_vector_type(4))) float;
typedef unsigned short u16;

__device__ __forceinline__ float leaky(float x) { return x >= 0.f ? x : SLOPE * x; }

// fp32 -> bf16 (round-to-nearest-even), bit pattern
__device__ __forceinline__ u16 f2bf(float f) {
  union { float f; unsigned u; } v; v.f = f;
  return (u16)((v.u + 0x7fffu + ((v.u >> 16) & 1u)) >> 16);
}
__device__ __forceinline__ float bf2f(u16 u) {
  union { unsigned u; float f; } v; v.u = ((unsigned)u) << 16;
  return v.f;
}

// XCD-affinity swizzle: block->XCD heuristic is blockIdx%8; pin graph g to
// XCD g%8 so producer/consumer blocks of one graph share an L2.
__device__ __forceinline__ bool swz(int b, int per_g, int& g, int& part) {
  const int xcd = b & 7;
  const int slot = b >> 3;
  g = xcd + 8 * (slot / per_g);
  part = slot % per_g;
  return g < NG;
}

// ---------------------------------------------------------------------------
// One-shot bf16 transpose of the four GEMM weight matrices: Wt[n][k]=W[k][n].
// ---------------------------------------------------------------------------
__global__ __launch_bounds__(256) void wt_k(const float* __restrict__ W1,
                                            const float* __restrict__ W2,
                                            const float* __restrict__ R1,
                                            const float* __restrict__ R2,
                                            u16* __restrict__ Wt1,
                                            u16* __restrict__ Wt2,
                                            u16* __restrict__ Rt1,
                                            u16* __restrict__ Rt2) {
  const int idx = blockIdx.x * 256 + threadIdx.x;  // 57344 total
  if (idx < FIN * HID) {
    const int n = idx >> 6, k = idx & 63;          // Wt1 [128][64]
    Wt1[idx] = f2bf(W1[k * HID + n]);
  } else {
    const int j = idx - FIN * HID;
    const int m = j >> 14, r = j & 16383;
    const int n = r >> 7, k = r & 127;
    const float* s = (m == 0) ? W2 : (m == 1) ? R1 : R2;
    u16* d = (m == 0) ? Wt2 : (m == 1) ? Rt1 : Rt2;
    d[r] = f2bf(s[k * HID + n]);
  }
}

// ---------------------------------------------------------------------------
// Per-graph CSR build, 4-edge batched loads. CSR record = packed dword
// {src_local:16 | bf16(w):16}; node segments 16B-aligned.
// ---------------------------------------------------------------------------
__global__ __launch_bounds__(1024) void build_k(const int* __restrict__ src,
                                                const int* __restrict__ dst,
                                                const float* __restrict__ ew,
                                                int* __restrict__ cin_,
                                                int* __restrict__ cout_,
                                                int* __restrict__ offs,
                                                unsigned* __restrict__ csr) {
  __shared__ int hin[NPG];
  __shared__ int hout[NPG];
  __shared__ int cur[NPG];
  __shared__ int wtot[16];
  int g, part;
  if (!swz(blockIdx.x, 1, g, part)) return;   // grid 8*13 = 104, 4 idle
  const int t = threadIdx.x;
  const int lane = t & 63, wave = t >> 6;
  const int nb = g * NPG, eb = g * EPG;
  if (t < NPG) { hin[t] = 0; hout[t] = 0; }
  __syncthreads();
  for (int e = t; e < EPG; e += 4096) {
    int s4[4], d4[4];
#pragma unroll
    for (int k = 0; k < 4; ++k) {
      const int ee = e + k * 1024;
      if (ee < EPG) { s4[k] = src[eb + ee]; d4[k] = dst[eb + ee]; }
      else d4[k] = -1;
    }
#pragma unroll
    for (int k = 0; k < 4; ++k)
      if (d4[k] >= 0) {
        atomicAdd(&hout[s4[k] - nb], 1);
        atomicAdd(&hin[d4[k] - nb], 1);
      }
  }
  __syncthreads();
  int v[4], vr[4];
  int loc = 0;
#pragma unroll
  for (int k = 0; k < 4; ++k) {
    const int idx = t * 4 + k;
    v[k] = (idx < NPG) ? hin[idx] : 0;
    vr[k] = (v[k] + 3) & ~3;          // 4-record-aligned segment size
    loc += vr[k];
  }
  int incl = loc;
#pragma unroll
  for (int d = 1; d < 64; d <<= 1) {
    const int x = __shfl_up(incl, d);
    if (lane >= d) incl += x;
  }
  if (lane == 63) wtot[wave] = incl;
  if (t < NPG) { cin_[nb + t] = hin[t]; cout_[nb + t] = hout[t]; }
  __syncthreads();
  int wexc = 0;
  for (int i = 0; i < wave; ++i) wexc += wtot[i];
  int run = g * CSRG + wexc + (incl - loc);
#pragma unroll
  for (int k = 0; k < 4; ++k) {
    const int idx = t * 4 + k;
    if (idx < NPG) {
      offs[nb + idx] = run;
      cur[idx] = run;
      run += vr[k];
    }
  }
  __syncthreads();
  for (int e = t; e < EPG; e += 4096) {
    int s4[4], d4[4]; float w4[4];
#pragma unroll
    for (int k = 0; k < 4; ++k) {
      const int ee = e + k * 1024;
      if (ee < EPG) { s4[k] = src[eb + ee]; d4[k] = dst[eb + ee]; w4[k] = ew[eb + ee]; }
      else d4[k] = -1;
    }
#pragma unroll
    for (int k = 0; k < 4; ++k)
      if (d4[k] >= 0) {
        const int pos = atomicAdd(&cur[d4[k] - nb], 1);
        csr[pos] = ((unsigned)(s4[k] - nb) << 16) | (unsigned)f2bf(w4[k]);
      }
  }
}

// ---------------------------------------------------------------------------
// Layer-1 GEMM (MFMA bf16), XCD-swizzled, register X-prefetch, bf16 output.
// ---------------------------------------------------------------------------
__global__ __launch_bounds__(256) void gemm1_k(const float* __restrict__ X,
                                               const u16* __restrict__ Wt,
                                               const int* __restrict__ cout_,
                                               u16* __restrict__ Y) {
  __shared__ u16 Xl[64 * FIN];
  __shared__ u16 Wl[HID * FIN];
  const int tid = threadIdx.x;
  const int wave = tid >> 6, lane = tid & 63, l15 = lane & 15, quad = lane >> 4;
  int g, part;
  if (!swz(blockIdx.x, 4, g, part)) return;
  const int base = g * NPG + part * NSTRIP;
  const int kq = tid & 15;
  const int srow = tid >> 4;

  for (int i = tid; i < HID * (FIN / 8); i += 256) {
    const int n = i >> 3, c = i & 7;
    const short8 w = *(const short8*)(Wt + n * FIN + c * 8);
    *(short8*)&Wl[n * FIN + ((c ^ (n & 7)) << 3)] = w;
  }
  float4 xpre[4];
#pragma unroll
  for (int it = 0; it < 4; ++it) {
    const int rowi = srow + it * 16;
    xpre[it] = (rowi < NSTRIP) ? *(const float4*)(X + (size_t)(base + rowi) * FIN + kq * 4)
                               : make_float4(0.f, 0.f, 0.f, 0.f);
  }
  for (int pass = 0; pass < 4; ++pass) {
    __syncthreads();
#pragma unroll
    for (int it = 0; it < 4; ++it) {
      const int r = srow + it * 16;
      ushort4 u = make_ushort4(f2bf(xpre[it].x), f2bf(xpre[it].y),
                               f2bf(xpre[it].z), f2bf(xpre[it].w));
      const int c = kq >> 1, half = kq & 1;
      *(ushort4*)&Xl[r * FIN + (((c ^ (r & 7)) << 3) | (half << 2))] = u;
    }
    __syncthreads();
    if (pass < 3) {
#pragma unroll
      for (int it = 0; it < 4; ++it) {
        const int rowi = (pass + 1) * 64 + srow + it * 16;
        xpre[it] = (rowi < NSTRIP) ? *(const float4*)(X + (size_t)(base + rowi) * FIN + kq * 4)
                                   : make_float4(0.f, 0.f, 0.f, 0.f);
      }
    }
    short8 a[2];
    const int arow = wave * 16 + l15;
#pragma unroll
    for (int kt = 0; kt < 2; ++kt)
      a[kt] = *(const short8*)&Xl[arow * FIN + (((kt * 4 + quad) ^ (l15 & 7)) << 3)];
    float sc[4];
    int rows[4];
#pragma unroll
    for (int r = 0; r < 4; ++r) {
      rows[r] = pass * 64 + wave * 16 + quad * 4 + r;
      sc[r] = (rows[r] < NSTRIP) ? rsqrtf(fmaxf((float)cout_[base + rows[r]], 1.0f)) : 0.f;
    }
#pragma unroll
    for (int ct = 0; ct < 8; ++ct) {
      f32x4 acc = {0.f, 0.f, 0.f, 0.f};
      const int brow = ct * 16 + l15;
#pragma unroll
      for (int kt = 0; kt < 2; ++kt) {
        const short8 b = *(const short8*)&Wl[brow * FIN + (((kt * 4 + quad) ^ (l15 & 7)) << 3)];
        acc = __builtin_amdgcn_mfma_f32_16x16x32_bf16(a[kt], b, acc, 0, 0, 0);
      }
      const int n = ct * 16 + l15;
#pragma unroll
      for (int r = 0; r < 4; ++r)
        if (rows[r] < NSTRIP) Y[(size_t)(base + rows[r]) * HID + n] = f2bf(acc[r] * sc[r]);
    }
  }
}

// inline GraphNorm affine from raw stats (replaces stats_k)
__device__ __forceinline__ void norm_affine(const float* sx, const float* sq,
                                            const float* alpha, const float* gamma,
                                            const float* beta, int g, int c8,
                                            float* Av, float* Bv) {
  const float inv = 1.0f / NPG;
#pragma unroll
  for (int j = 0; j < 8; ++j) {
    const int f = c8 * 8 + j;
    const float mean = sx[g * HID + f] * inv;
    const float ex2 = sq[g * HID + f] * inv;
    const float am = alpha[f] * mean;
    const float var = fmaxf(ex2 - 2.0f * am * mean + am * am, 0.0f);
    const float A = gamma[f] * rsqrtf(var + EPSV);
    Av[j] = A;
    Bv[j] = beta[f] - A * am;
  }
}

// ---------------------------------------------------------------------------
// Layer-2 GEMM (MFMA bf16), fused norm (inline stats), X prefetch.
// ---------------------------------------------------------------------------
__global__ __launch_bounds__(256) void gemm_norm_k(const u16* __restrict__ Xb,
                                                   const u16* __restrict__ Wt,
                                                   const float* __restrict__ sx,
                                                   const float* __restrict__ sq,
                                                   const float* __restrict__ alpha,
                                                   const float* __restrict__ gamma,
                                                   const float* __restrict__ beta,
                                                   const int* __restrict__ cout_,
                                                   u16* __restrict__ Y) {
  __shared__ u16 Xl[64 * HID];
  __shared__ u16 Wl[HID * HID];
  const int tid = threadIdx.x;
  const int wave = tid >> 6, lane = tid & 63, l15 = lane & 15, quad = lane >> 4;
  int g, part;
  if (!swz(blockIdx.x, 4, g, part)) return;
  const int base = g * NPG + part * NSTRIP;
  const int c8 = tid & 15;
  const int srow = tid >> 4;

  for (int i = tid; i < HID * (HID / 8); i += 256) {
    const int n = i >> 4, c = i & 15;
    const short8 w = *(const short8*)(Wt + n * HID + c * 8);
    *(short8*)&Wl[n * HID + ((c ^ (n & 15)) << 3)] = w;
  }
  float Av[8], Bv[8];
  norm_affine(sx, sq, alpha, gamma, beta, g, c8, Av, Bv);
  const short8 z8 = {0, 0, 0, 0, 0, 0, 0, 0};
  short8 xpre[4];
#pragma unroll
  for (int it = 0; it < 4; ++it) {
    const int rowi = srow + it * 16;
    xpre[it] = (rowi < NSTRIP) ? *(const short8*)(Xb + (size_t)(base + rowi) * HID + c8 * 8) : z8;
  }
  for (int pass = 0; pass < 4; ++pass) {
    __syncthreads();
#pragma unroll
    for (int it = 0; it < 4; ++it) {
      const int r = srow + it * 16;
      const int rowi = pass * 64 + r;
      short8 o = z8;
      if (rowi < NSTRIP) {
#pragma unroll
        for (int j = 0; j < 8; ++j)
          o[j] = (short)f2bf(leaky(fmaf(Av[j], bf2f((u16)xpre[it][j]), Bv[j])));
      }
      *(short8*)&Xl[r * HID + ((c8 ^ (r & 15)) << 3)] = o;
    }
    __syncthreads();
    if (pass < 3) {
#pragma unroll
      for (int it = 0; it < 4; ++it) {
        const int rowi = (pass + 1) * 64 + srow + it * 16;
        xpre[it] = (rowi < NSTRIP) ? *(const short8*)(Xb + (size_t)(base + rowi) * HID + c8 * 8) : z8;
      }
    }
    short8 a[4];
    const int arow = wave * 16 + l15;
#pragma unroll
    for (int kt = 0; kt < 4; ++kt)
      a[kt] = *(const short8*)&Xl[arow * HID + (((kt * 4 + quad) ^ l15) << 3)];
    float sc[4];
    int rows[4];
#pragma unroll
    for (int r = 0; r < 4; ++r) {
      rows[r] = pass * 64 + wave * 16 + quad * 4 + r;
      sc[r] = (rows[r] < NSTRIP) ? rsqrtf(fmaxf((float)cout_[base + rows[r]], 1.0f)) : 0.f;
    }
#pragma unroll
    for (int ct = 0; ct < 8; ++ct) {
      f32x4 acc = {0.f, 0.f, 0.f, 0.f};
      const int brow = ct * 16 + l15;
#pragma unroll
      for (int kt = 0; kt < 4; ++kt) {
        const short8 b = *(const short8*)&Wl[brow * HID + (((kt * 4 + quad) ^ l15) << 3)];
        acc = __builtin_amdgcn_mfma_f32_16x16x32_bf16(a[kt], b, acc, 0, 0, 0);
      }
      const int n = ct * 16 + l15;
#pragma unroll
      for (int r = 0; r < 4; ++r)
        if (rows[r] < NSTRIP) Y[(size_t)(base + rows[r]) * HID + n] = f2bf(acc[r] * sc[r]);
    }
  }
}

// ---------------------------------------------------------------------------
// Readout phi+pool (MFMA bf16): 48 KB LDS, inline stats, X prefetch.
// ---------------------------------------------------------------------------
struct RedT { float red[16][HID]; float hred[16][HID]; };  // 16 KB
union ShT { u16 Xl[64 * HID]; RedT r; };                   // 16 KB

__global__ __launch_bounds__(256) void phi_pool_k(const u16* __restrict__ Xb,
                                                  const float* __restrict__ sx,
                                                  const float* __restrict__ sq,
                                                  const float* __restrict__ alpha,
                                                  const float* __restrict__ gamma,
                                                  const float* __restrict__ beta,
                                                  const u16* __restrict__ Wt,
                                                  const float* __restrict__ b1,
                                                  float* __restrict__ phi_sum,
                                                  float* __restrict__ h_sum) {
  __shared__ ShT sh;                    // 16 KB (Xl, then red/hred)
  __shared__ u16 Wl[HID * HID];         // 32 KB  -> 48 KB total
  const int tid = threadIdx.x;
  const int wave = tid >> 6, lane = tid & 63, l15 = lane & 15, quad = lane >> 4;
  int g, part;
  if (!swz(blockIdx.x, 4, g, part)) return;
  const int base = g * NPG + part * NSTRIP;
  const int c8 = tid & 15;
  const int srow = tid >> 4;

  for (int i = tid; i < HID * (HID / 8); i += 256) {
    const int n = i >> 4, c = i & 15;
    const short8 w = *(const short8*)(Wt + n * HID + c * 8);
    *(short8*)&Wl[n * HID + ((c ^ (n & 15)) << 3)] = w;
  }
  float Av[8], Bv[8];
  norm_affine(sx, sq, alpha, gamma, beta, g, c8, Av, Bv);
  float bcol[8];
#pragma unroll
  for (int ct = 0; ct < 8; ++ct) bcol[ct] = b1[ct * 16 + l15];

  float pooled[8] = {0.f, 0.f, 0.f, 0.f, 0.f, 0.f, 0.f, 0.f};
  float hp[8] = {0.f, 0.f, 0.f, 0.f, 0.f, 0.f, 0.f, 0.f};
  const short8 z8 = {0, 0, 0, 0, 0, 0, 0, 0};
  short8 xpre[4];
#pragma unroll
  for (int it = 0; it < 4; ++it) {
    const int rowi = srow + it * 16;
    xpre[it] = (rowi < NSTRIP) ? *(const short8*)(Xb + (size_t)(base + rowi) * HID + c8 * 8) : z8;
  }
  for (int pass = 0; pass < 4; ++pass) {
    __syncthreads();
#pragma unroll
    for (int it = 0; it < 4; ++it) {
      const int r = srow + it * 16;
      const int rowi = pass * 64 + r;
      short8 o = z8;
      if (rowi < NSTRIP) {
#pragma unroll
        for (int j = 0; j < 8; ++j) {
          const float xn = leaky(fmaf(Av[j], bf2f((u16)xpre[it][j]), Bv[j]));
          hp[j] += xn;
          o[j] = (short)f2bf(xn);
        }
      }
      *(short8*)&sh.Xl[r * HID + ((c8 ^ (r & 15)) << 3)] = o;
    }
    __syncthreads();
    if (pass < 3) {
#pragma unroll
      for (int it = 0; it < 4; ++it) {
        const int rowi = (pass + 1) * 64 + srow + it * 16;
        xpre[it] = (rowi < NSTRIP) ? *(const short8*)(Xb + (size_t)(base + rowi) * HID + c8 * 8) : z8;
      }
    }
    short8 a[4];
    const int arow = wave * 16 + l15;
#pragma unroll
    for (int kt = 0; kt < 4; ++kt)
      a[kt] = *(const short8*)&sh.Xl[arow * HID + (((kt * 4 + quad) ^ l15) << 3)];
#pragma unroll
    for (int ct = 0; ct < 8; ++ct) {
      f32x4 acc = {0.f, 0.f, 0.f, 0.f};
      const int brow = ct * 16 + l15;
#pragma unroll
      for (int kt = 0; kt < 4; ++kt) {
        const short8 b = *(const short8*)&Wl[brow * HID + (((kt * 4 + quad) ^ l15) << 3)];
        acc = __builtin_amdgcn_mfma_f32_16x16x32_bf16(a[kt], b, acc, 0, 0, 0);
      }
#pragma unroll
      for (int r = 0; r < 4; ++r) {
        const int rowi = pass * 64 + wave * 16 + quad * 4 + r;
        if (rowi < NSTRIP) pooled[ct] += leaky(acc[r] + bcol[ct]);
      }
    }
  }
  __syncthreads();   // all Xl reads done -> safe to overwrite with red/hred
  const int qi = wave * 4 + quad;
#pragma unroll
  for (int ct = 0; ct < 8; ++ct) sh.r.red[qi][ct * 16 + l15] = pooled[ct];
#pragma unroll
  for (int j = 0; j < 8; ++j) sh.r.hred[tid >> 4][(tid & 15) * 8 + j] = hp[j];
  __syncthreads();
  if (tid < HID) {
    float s = 0.f;
#pragma unroll
    for (int q = 0; q < 16; ++q) s += sh.r.red[q][tid];
    unsafeAtomicAdd(&phi_sum[g * HID + tid], s);
  } else {
    const int t = tid - HID;
    float s = 0.f;
#pragma unroll
    for (int rr = 0; rr < 16; ++rr) s += sh.r.hred[rr][t];
    unsafeAtomicAdd(&h_sum[g * HID + t], s);
  }
}

// ---------------------------------------------------------------------------
// Gather: scalar-pipe CSR records, FOUR independent node-chains per wave
// (groups of 4/4/2 over the wave's 10 nodes) -> up to 16 outstanding vmem.
// ---------------------------------------------------------------------------
__global__ __launch_bounds__(256) void gather_k(const u16* __restrict__ H,
                                                const unsigned* __restrict__ csr,
                                                const int* __restrict__ offs,
                                                const int* __restrict__ cin_,
                                                u16* __restrict__ AGG,
                                                float* __restrict__ sx,
                                                float* __restrict__ sq) {
  __shared__ float redx[4][HID];
  __shared__ float redq[4][HID];
  const int wave = threadIdx.x >> 6;
  const int lane = threadIdx.x & 63;
  int g, part;
  if (!swz(blockIdx.x, 25, g, part)) return;
  const int nb = g * NPG;
  const int base = nb + part * GSN;
  const int loff = lane * 2;
  const u16* __restrict__ Hg = H + (size_t)nb * HID;

  float sxa = 0.f, sxb = 0.f, sqa = 0.f, sqb = 0.f;
  for (int it = 0; it < 3; ++it) {            // node groups: 4, 4, 2
    const int nc = (it < 2) ? 4 : 2;
    int nn[4], off[4], cnt[4], c4[4];
    float isq[4];
    const uint4* p[4];
#pragma unroll
    for (int c = 0; c < 4; ++c) {
      const int j = it * 4 + c;
      const int node = base + wave + ((j < 10) ? j : 0) * 4;
      nn[c] = node;
      const int nu = __builtin_amdgcn_readfirstlane(node);
      off[c] = __builtin_amdgcn_readfirstlane(offs[nu]);
      cnt[c] = (c < nc) ? __builtin_amdgcn_readfirstlane(cin_[nu]) : 0;
      c4[c] = cnt[c] >> 2;
      isq[c] = rsqrtf(fmaxf((float)cnt[c], 1.0f));
      p[c] = (const uint4*)__builtin_assume_aligned(csr + off[c], 16);
    }
    float ax[4] = {0.f, 0.f, 0.f, 0.f};
    float ay[4] = {0.f, 0.f, 0.f, 0.f};
    int common = min(c4[0], c4[1]);
    if (nc == 4) common = min(common, min(c4[2], c4[3]));
    for (int t = 0; t < common; ++t) {        // interleaved: nc chains in flight
      uint4 r[4];
      unsigned u[4][4];
#pragma unroll
      for (int c = 0; c < 4; ++c)
        if (c < nc) {
          r[c] = p[c][t];
          u[c][0] = *(const unsigned*)(Hg + (size_t)(r[c].x >> 16) * HID + loff);
          u[c][1] = *(const unsigned*)(Hg + (size_t)(r[c].y >> 16) * HID + loff);
          u[c][2] = *(const unsigned*)(Hg + (size_t)(r[c].z >> 16) * HID + loff);
          u[c][3] = *(const unsigned*)(Hg + (size_t)(r[c].w >> 16) * HID + loff);
        }
#pragma unroll
      for (int c = 0; c < 4; ++c)
        if (c < nc) {
          const float w0 = bf2f((u16)(r[c].x & 0xffffu));
          const float w1 = bf2f((u16)(r[c].y & 0xffffu));
          const float w2 = bf2f((u16)(r[c].z & 0xffffu));
          const float w3 = bf2f((u16)(r[c].w & 0xffffu));
          ax[c] = fmaf(w0, __uint_as_float(u[c][0] << 16), ax[c]);
          ay[c] = fmaf(w0, __uint_as_float(u[c][0] & 0xffff0000u), ay[c]);
          ax[c] = fmaf(w1, __uint_as_float(u[c][1] << 16), ax[c]);
          ay[c] = fmaf(w1, __uint_as_float(u[c][1] & 0xffff0000u), ay[c]);
          ax[c] = fmaf(w2, __uint_as_float(u[c][2] << 16), ax[c]);
          ay[c] = fmaf(w2, __uint_as_float(u[c][2] & 0xffff0000u), ay[c]);
          ax[c] = fmaf(w3, __uint_as_float(u[c][3] << 16), ax[c]);
          ay[c] = fmaf(w3, __uint_as_float(u[c][3] & 0xffff0000u), ay[c]);
        }
    }
#pragma unroll
    for (int c = 0; c < 4; ++c) {             // per-chain drains (chunks)
      for (int t = common; t < c4[c]; ++t) {
        const uint4 r = p[c][t];
        const unsigned u0 = *(const unsigned*)(Hg + (size_t)(r.x >> 16) * HID + loff);
        const unsigned u1 = *(const unsigned*)(Hg + (size_t)(r.y >> 16) * HID + loff);
        const unsigned u2 = *(const unsigned*)(Hg + (size_t)(r.z >> 16) * HID + loff);
        const unsigned u3 = *(const unsigned*)(Hg + (size_t)(r.w >> 16) * HID + loff);
        const float w0 = bf2f((u16)(r.x & 0xffffu));
        const float w1 = bf2f((u16)(r.y & 0xffffu));
        const float w2 = bf2f((u16)(r.z & 0xffffu));
        const float w3 = bf2f((u16)(r.w & 0xffffu));
        ax[c] = fmaf(w0, __uint_as_float(u0 << 16), ax[c]);
        ay[c] = fmaf(w0, __uint_as_float(u0 & 0xffff0000u), ay[c]);
        ax[c] = fmaf(w1, __uint_as_float(u1 << 16), ax[c]);
        ay[c] = fmaf(w1, __uint_as_float(u1 & 0xffff0000u), ay[c]);
        ax[c] = fmaf(w2, __uint_as_float(u2 << 16), ax[c]);
        ay[c] = fmaf(w2, __uint_as_float(u2 & 0xffff0000u), ay[c]);
        ax[c] = fmaf(w3, __uint_as_float(u3 << 16), ax[c]);
        ay[c] = fmaf(w3, __uint_as_float(u3 & 0xffff0000u), ay[c]);
      }
      for (int k = c4[c] << 2; k < cnt[c]; ++k) {  // tails (0-3 records)
        const unsigned r0 = csr[off[c] + k];
        const float w = bf2f((u16)(r0 & 0xffffu));
        const unsigned u0 = *(const unsigned*)(Hg + (size_t)(r0 >> 16) * HID + loff);
        ax[c] = fmaf(w, __uint_as_float(u0 << 16), ax[c]);
        ay[c] = fmaf(w, __uint_as_float(u0 & 0xffff0000u), ay[c]);
      }
    }
#pragma unroll
    for (int c = 0; c < 4; ++c)
      if (c < nc) {
        const float rx = ax[c] * isq[c];
        const float ry = ay[c] * isq[c];
        *(unsigned*)(AGG + (size_t)nn[c] * HID + loff) =
            (unsigned)f2bf(rx) | ((unsigned)f2bf(ry) << 16);
        sxa += rx; sxb += ry;
        sqa += rx * rx; sqb += ry * ry;
      }
  }
  redx[wave][loff] = sxa; redx[wave][loff + 1] = sxb;
  redq[wave][loff] = sqa; redq[wave][loff + 1] = sqb;
  __syncthreads();
  const int tid = threadIdx.x;
  if (tid < HID) {
    unsafeAtomicAdd(&sx[g * HID + tid],
                    redx[0][tid] + redx[1][tid] + redx[2][tid] + redx[3][tid]);
  } else {
    const int t = tid - HID;
    unsafeAtomicAdd(&sq[g * HID + t],
                    redq[0][t] + redq[1][t] + redq[2][t] + redq[3][t]);
  }
}

// ---------------------------------------------------------------------------
// Readout part 2.
// ---------------------------------------------------------------------------
__global__ __launch_bounds__(64) void finalize_k(const float* __restrict__ phi_sum,
                                                 const float* __restrict__ h_sum,
                                                 const float* __restrict__ w2,
                                                 const float* __restrict__ b2,
                                                 float* __restrict__ out,
                                                 int roff, int moff) {
  const int g = blockIdx.x;
  const int j = threadIdx.x;  // 0..63
  float acc = b2[j];
#pragma unroll 8
  for (int k = 0; k < HID; ++k)
    acc += (phi_sum[g * HID + k] * (1.0f / NPG)) * w2[k * RD + j];
  const float r = leaky(acc);
  out[g * 384 + roff + j] = leaky(r);
  out[g * 384 + moff + j] = leaky(h_sum[g * HID + j] * (1.0f / NPG));
  out[g * 384 + moff + 64 + j] = leaky(h_sum[g * HID + 64 + j] * (1.0f / NPG));
}

// ---------------------------------------------------------------------------
extern "C" void kernel_launch(void* const* d_in, const int* in_sizes, int n_in,
                              void* d_out, int out_size, void* d_ws, size_t ws_size,
                              hipStream_t stream) {
  const float* node_feats = (const float*)d_in[0];
  const float* ew   = (const float*)d_in[1];
  const float* W1   = (const float*)d_in[2];
  const float* W2   = (const float*)d_in[3];
  const float* g1a  = (const float*)d_in[4];
  const float* g1g  = (const float*)d_in[5];
  const float* g1b  = (const float*)d_in[6];
  const float* g2a  = (const float*)d_in[7];
  const float* g2g  = (const float*)d_in[8];
  const float* g2b  = (const float*)d_in[9];
  const float* r1w1 = (const float*)d_in[10];
  const float* r1b1 = (const float*)d_in[11];
  const float* r1w2 = (const float*)d_in[12];
  const float* r1b2 = (const float*)d_in[13];
  const float* r2w1 = (const float*)d_in[14];
  const float* r2b1 = (const float*)d_in[15];
  const float* r2w2 = (const float*)d_in[16];
  const float* r2b2 = (const float*)d_in[17];
  const int* src = (const int*)d_in[18];
  const int* dst = (const int*)d_in[19];
  float* out = (float*)d_out;

  // workspace layout (zeroed region first: phi/h pooled sums + sx/sq)
  char* wsb = (char*)d_ws;
  float* ps1     = (float*)wsb;                       // NG*HID x8, zeroed
  float* hs1     = ps1 + NG * HID;
  float* ps2     = hs1 + NG * HID;
  float* hs2     = ps2 + NG * HID;
  float* sx1     = hs2 + NG * HID;
  float* sq1     = sx1 + NG * HID;
  float* sx2     = sq1 + NG * HID;
  float* sq2     = sx2 + NG * HID;
  int*   cin     = (int*)(sq2 + NG * HID);            // NN (direct store)
  int*   cout_   = cin + NN;                          // NN (direct store)
  int*   offs    = cout_ + NN;                        // NN (direct store)
  unsigned* csr  = (unsigned*)(offs + NN);            // NG*CSRG packed dwords (8 MB)
  u16*   Wt1     = (u16*)(csr + (size_t)NG * CSRG);   // 128*64
  u16*   Wt2     = Wt1 + HID * FIN;                   // 128*128 x3
  u16*   Rt1     = Wt2 + HID * HID;
  u16*   Rt2     = Rt1 + HID * HID;
  u16*   bufA    = Rt2 + HID * HID;                   // NN*HID bf16
  u16*   bufB    = bufA + (size_t)NN * HID;           // NN*HID bf16

  hipMemsetAsync(d_ws, 0, (size_t)(8 * NG * HID) * sizeof(float), stream);

  // weight transpose + per-graph CSR build (per call)
  wt_k<<<(FIN * HID + 3 * HID * HID) / 256, 256, 0, stream>>>(
      W1, W2, r1w1, r2w1, Wt1, Wt2, Rt1, Rt2);
  build_k<<<8 * 13, 1024, 0, stream>>>(src, dst, ew, cin, cout_, offs, csr);

  const int gemm_grid = 8 * 4 * 13;     // XCD-swizzled, 4 strips/graph
  const int gather_grid = 8 * 25 * 13;  // XCD-swizzled, 25 strips/graph

  // ---- layer 1 ----
  gemm1_k<<<gemm_grid, 256, 0, stream>>>(node_feats, Wt1, cout_, bufA);
  gather_k<<<gather_grid, 256, 0, stream>>>(bufA, csr, offs, cin, bufB, sx1, sq1);
  phi_pool_k<<<gemm_grid, 256, 0, stream>>>(bufB, sx1, sq1, g1a, g1g, g1b,
                                            Rt1, r1b1, ps1, hs1);
  finalize_k<<<NG, 64, 0, stream>>>(ps1, hs1, r1w2, r1b2, out, 0, 64);

  // ---- layer 2 ----
  gemm_norm_k<<<gemm_grid, 256, 0, stream>>>(bufB, Wt2, sx1, sq1, g1a, g1g, g1b,
                                             cout_, bufA);
  gather_k<<<gather_grid, 256, 0, stream>>>(bufA, csr, offs, cin, bufB, sx2, sq2);
  phi_pool_k<<<gemm_grid, 256, 0, stream>>>(bufB, sx2, sq2, g2a, g2g, g2b,
                                            Rt2, r2b1, ps2, hs2);
  finalize_k<<<NG, 64, 0, stream>>>(ps2, hs2, r2w2, r2b2, out, 192, 256);
}